// Round 12
// baseline (260.343 us; speedup 1.0000x reference)
//
#include <hip/hip_runtime.h>
#include <cstddef>

#define NT    32768
#define CCH   128
#define BB    64
#define NNODE 512
#define NHEAD 4
#define DHEAD 32
#define EE    524288
#define EPS   1e-5f
#define MAXDEG 96
#define VTS   524

typedef unsigned short u16;
typedef unsigned int   u32;
typedef __attribute__((ext_vector_type(8))) short short8;
typedef __attribute__((ext_vector_type(4))) short short4v;
typedef __attribute__((ext_vector_type(4))) float f32x4;

__device__ __forceinline__ float b2f(u32 w) { return __uint_as_float(w << 16); }
__device__ __forceinline__ u16 f2b(float f) {
    u32 u = __float_as_uint(f);
    u += 0x7FFF + ((u >> 16) & 1);   // RNE
    return (u16)(u >> 16);
}

// ---------------- prep: bf16 conversion (blocks 0..2119) AND bucket fill (blocks 2120..2631) ----------------
// fill: 4 consecutive edges per thread (int4 loads), u16 bucket (src < 32768).
__global__ __launch_bounds__(256) void prep_kernel(const float* __restrict__ x,
                                                   const float* __restrict__ Wc,
                                                   const float* __restrict__ Wqkv,
                                                   const float* __restrict__ Wo,
                                                   const float* __restrict__ Wm1,
                                                   const float* __restrict__ Wm2,
                                                   u16* __restrict__ xb,
                                                   u16* __restrict__ Wcb,
                                                   u16* __restrict__ Wqkvb,
                                                   u16* __restrict__ Wob,
                                                   u16* __restrict__ Wm1b,
                                                   u16* __restrict__ Wm2b,
                                                   const int* __restrict__ ei,
                                                   int* __restrict__ cursor,
                                                   u16* __restrict__ bucket) {
    if (blockIdx.x >= 2120) {
        int t = (blockIdx.x - 2120) * 256 + threadIdx.x;
        int e = t * 4;
        int4 sv = *(const int4*)(ei + e);
        int4 dv = *(const int4*)(ei + EE + e);
        int p0 = atomicAdd(cursor + dv.x, 1);
        int p1 = atomicAdd(cursor + dv.y, 1);
        int p2 = atomicAdd(cursor + dv.z, 1);
        int p3 = atomicAdd(cursor + dv.w, 1);
        if (p0 < MAXDEG) bucket[dv.x * MAXDEG + p0] = (u16)sv.x;
        if (p1 < MAXDEG) bucket[dv.y * MAXDEG + p1] = (u16)sv.y;
        if (p2 < MAXDEG) bucket[dv.z * MAXDEG + p2] = (u16)sv.z;
        if (p3 < MAXDEG) bucket[dv.w * MAXDEG + p3] = (u16)sv.w;
        return;
    }
    int r = blockIdx.x * 256 + threadIdx.x;
    const float* src; u16* dst;
    if (r < 524288) { src = x; dst = xb; }
    else if ((r -= 524288) < 2048) { src = Wc; dst = Wcb; }
    else if ((r -= 2048) < 6144) { src = Wqkv; dst = Wqkvb; }
    else if ((r -= 6144) < 2048) { src = Wo; dst = Wob; }
    else if ((r -= 2048) < 4096) { src = Wm1; dst = Wm1b; }
    else { r -= 4096; src = Wm2; dst = Wm2b; }
    size_t base = (size_t)r * 8;
    float4 a = *(const float4*)(src + base);
    float4 b = *(const float4*)(src + base + 4);
    uint4 u;
    u.x = (u32)f2b(a.x) | ((u32)f2b(a.y) << 16);
    u.y = (u32)f2b(a.z) | ((u32)f2b(a.w) << 16);
    u.z = (u32)f2b(b.x) | ((u32)f2b(b.y) << 16);
    u.w = (u32)f2b(b.z) | ((u32)f2b(b.w) << 16);
    *(uint4*)(dst + base) = u;
}

// ---------------- stage2: aggregate (blocks 0..4095) | QKV GEMM (blocks 4096..4863) ----------------
__global__ __launch_bounds__(256) void stage2_kernel(const u16* __restrict__ bucket,
                                                     const int* __restrict__ cursor,
                                                     const u16* __restrict__ xb,
                                                     u16* __restrict__ aggb,
                                                     const u16* __restrict__ Wqkvb,
                                                     const float* __restrict__ bqkv,
                                                     u16* __restrict__ qkvb) {
    __shared__ __align__(16) char smem[26624];
    int tid = threadIdx.x;
    if (blockIdx.x < 4096) {
        int* srcs = (int*)smem;              // [8][96]
        int ln = tid >> 5;
        int c4 = tid & 31;
        int n = blockIdx.x * 8 + ln;
        int d = min(cursor[n], MAXDEG);
        for (int j = c4; j < d; j += 32) srcs[ln * MAXDEG + j] = bucket[n * MAXDEG + j];
        __syncthreads();
        float s0 = 0.f, s1 = 0.f, s2 = 0.f, s3 = 0.f;
        for (int j = 0; j < d; ++j) {
            uint2 w = *(const uint2*)(xb + (size_t)srcs[ln * MAXDEG + j] * CCH + c4 * 4);
            s0 += b2f(w.x & 0xffffu);
            s1 += b2f(w.x >> 16);
            s2 += b2f(w.y & 0xffffu);
            s3 += b2f(w.y >> 16);
        }
        float inv = 1.0f / fmaxf((float)d, 1.0f);
        uint2 out;
        out.x = (u32)f2b(s0 * inv) | ((u32)f2b(s1 * inv) << 16);
        out.y = (u32)f2b(s2 * inv) | ((u32)f2b(s3 * inv) << 16);
        *(uint2*)(aggb + (size_t)n * CCH + c4 * 4) = out;
        return;
    }
    // ---- QKV GEMM slice: y in 0..2, 256 m-blocks each ----
    int bx = blockIdx.x - 4096;
    int y = bx >> 8;
    int m0 = (bx & 255) * 128;
    const u16* W = Wqkvb + (size_t)y * 128 * 128;
    const float* bias = bqkv + y * 128;
    u16* As = (u16*)smem;                 // 8192 B
    u16* Bs = (u16*)(smem + 8192);        // 8192 B
    u16* Cs = (u16*)(smem + 16384);       // 9216 B

    int lane = tid & 63, wave = tid >> 6;
    int wm = (wave & 1) * 64, wn = (wave >> 1) * 64;
    int l15 = lane & 15, l4 = lane >> 4;

    f32x4 zero = {0.f, 0.f, 0.f, 0.f};
    f32x4 acc[4][4];
#pragma unroll
    for (int i = 0; i < 4; ++i)
#pragma unroll
        for (int j = 0; j < 4; ++j) acc[i][j] = zero;

    int srow = tid >> 2;
    int scol = (tid & 3) * 8;

    uint4 a0 = *(const uint4*)(xb + (size_t)(m0 + srow) * 128 + scol);
    uint4 a1 = *(const uint4*)(xb + (size_t)(m0 + srow + 64) * 128 + scol);
    uint4 b0 = *(const uint4*)(W + (size_t)srow * 128 + scol);
    uint4 b1 = *(const uint4*)(W + (size_t)(srow + 64) * 128 + scol);
    for (int ki = 0; ki < 4; ++ki) {
        if (ki) __syncthreads();
        *(uint4*)&As[srow * 32 + scol] = a0;
        *(uint4*)&As[(srow + 64) * 32 + scol] = a1;
        *(uint4*)&Bs[srow * 32 + scol] = b0;
        *(uint4*)&Bs[(srow + 64) * 32 + scol] = b1;
        if (ki < 3) {
            int k0 = (ki + 1) * 32;
            a0 = *(const uint4*)(xb + (size_t)(m0 + srow) * 128 + k0 + scol);
            a1 = *(const uint4*)(xb + (size_t)(m0 + srow + 64) * 128 + k0 + scol);
            b0 = *(const uint4*)(W + (size_t)srow * 128 + k0 + scol);
            b1 = *(const uint4*)(W + (size_t)(srow + 64) * 128 + k0 + scol);
        }
        __syncthreads();
        short8 af[4], bf[4];
#pragma unroll
        for (int t = 0; t < 4; ++t) {
            af[t] = *(const short8*)&As[(wm + t * 16 + l15) * 32 + l4 * 8];
            bf[t] = *(const short8*)&Bs[(wn + t * 16 + l15) * 32 + l4 * 8];
        }
#pragma unroll
        for (int mt = 0; mt < 4; ++mt)
#pragma unroll
            for (int nt = 0; nt < 4; ++nt)
                acc[mt][nt] = __builtin_amdgcn_mfma_f32_16x16x32_bf16(af[mt], bf[nt], acc[mt][nt], 0, 0, 0);
    }

    int rl = lane >> 3;
    int cg = lane & 7;
    u16* Cw = Cs + wave * 16 * 72;
#pragma unroll
    for (int mt = 0; mt < 4; ++mt) {
#pragma unroll
        for (int nt = 0; nt < 4; ++nt) {
            float bs = bias[wn + nt * 16 + l15];
#pragma unroll
            for (int r = 0; r < 4; ++r)
                Cw[(l4 * 4 + r) * 72 + nt * 16 + l15] = f2b(acc[mt][nt][r] + bs);
        }
#pragma unroll
        for (int p = 0; p < 2; ++p) {
            int lrow = p * 8 + rl;
            uint4 wv = *(const uint4*)&Cw[lrow * 72 + cg * 8];
            int grow = m0 + wm + mt * 16 + lrow;
            *(uint4*)(qkvb + (size_t)grow * 384 + y * 128 + wn + cg * 8) = wv;
        }
    }
}

// ---------------- MFMA flash attention, S^T chained, 8 waves x 4 q-tiles ----------------
__global__ __launch_bounds__(512) void attn_mfma(const u16* __restrict__ qkv,
                                                 u16* __restrict__ o) {
    __shared__ __align__(16) u16 Ks[512 * 40];      // 40 KB
    __shared__ __align__(16) u16 Vt[32 * VTS];      // 32.75 KB (stride 524: bank-friendly)
    int bh = blockIdx.x;
    int b = bh >> 2, h = bh & 3;
    int tid = threadIdx.x;
    int lane = tid & 63, wave = tid >> 6;
    int quad = lane >> 4, l15 = lane & 15;
    const float scale = 0.1767766952966369f;  // 1/sqrt(32)

    const u16* kvbase = qkv + (size_t)b * 512 * 384 + 128 + h * 32;
    for (int idx = tid; idx < 2048; idx += 512) {
        int row = idx >> 2, c = idx & 3;
        *(uint4*)&Ks[row * 40 + c * 8] = *(const uint4*)(kvbase + (size_t)row * 384 + c * 8);
    }
    for (int idx = tid; idx < 2048; idx += 512) {
        int row = idx >> 2, c = idx & 3;
        uint4 u = *(const uint4*)(kvbase + 128 + (size_t)row * 384 + c * 8);
        u16 e[8];
        *(uint4*)e = u;
#pragma unroll
        for (int i = 0; i < 8; ++i) Vt[(c * 8 + i) * VTS + row] = e[i];
    }
    __syncthreads();

    f32x4 zero = {0.f, 0.f, 0.f, 0.f};
    for (int qt = 0; qt < 4; ++qt) {
        int qbase = wave * 64 + qt * 16;
        short8 qf = *(const short8*)(qkv + (size_t)(b * 512 + qbase + l15) * 384 + h * 32 + quad * 8);
        float lq = 0.f;
        f32x4 oa[2] = {zero, zero};

        for (int kv0 = 0; kv0 < 512; kv0 += 64) {
            f32x4 s[4];
#pragma unroll
            for (int t = 0; t < 4; ++t) {
                short8 kb = *(const short8*)&Ks[(kv0 + t * 16 + l15) * 40 + quad * 8];
                s[t] = __builtin_amdgcn_mfma_f32_16x16x32_bf16(kb, qf, zero, 0, 0, 0);
            }
            short8 pa[4];
#pragma unroll
            for (int t = 0; t < 4; ++t) {
                float p0 = __expf(s[t][0] * scale);
                float p1 = __expf(s[t][1] * scale);
                float p2 = __expf(s[t][2] * scale);
                float p3 = __expf(s[t][3] * scale);
                lq += (p0 + p1) + (p2 + p3);
                short8 a8 = {(short)f2b(p0), (short)f2b(p1), (short)f2b(p2), (short)f2b(p3), 0, 0, 0, 0};
                pa[t] = a8;
            }
#pragma unroll
            for (int t = 0; t < 4; ++t) {
                int tbase = kv0 + t * 16;
#pragma unroll
                for (int n = 0; n < 2; ++n) {
                    short4v v4 = *(const short4v*)&Vt[(n * 16 + l15) * VTS + tbase + quad * 4];
                    short8 vb = {v4.x, v4.y, v4.z, v4.w, 0, 0, 0, 0};
                    oa[n] = __builtin_amdgcn_mfma_f32_16x16x32_bf16(pa[t], vb, oa[n], 0, 0, 0);
                }
            }
        }
        lq += __shfl_xor(lq, 16);
        lq += __shfl_xor(lq, 32);
        u16* op = o + (size_t)(b * 512 + qbase) * 128 + h * 32;
#pragma unroll
        for (int r = 0; r < 4; ++r) {
            float Lr = __shfl(lq, quad * 4 + r);
            float inv = 1.0f / Lr;
#pragma unroll
            for (int n = 0; n < 2; ++n)
                op[(quad * 4 + r) * 128 + n * 16 + l15] = f2b(oa[n][r] * inv);
        }
    }
}

// ---------------- bf16 MFMA GEMM (Wc, Wo, MLP2): dbuf + wide-store epilogue ----------------
template <bool RELU, int RESID, bool STATS>
__global__ __launch_bounds__(256) void gemm_mfma(const u16* __restrict__ A,
                                                 const u16* __restrict__ W,
                                                 const float* __restrict__ bias,
                                                 const u16* __restrict__ residb,
                                                 u16* __restrict__ outb,
                                                 float* __restrict__ sum,
                                                 float* __restrict__ sumsq,
                                                 int M, int N, int K) {
    __shared__ u16 As[128 * 32];
    __shared__ u16 Bs[128 * 32];
    __shared__ u16 Cs[4][16 * 72];
    __shared__ float csum[128];
    __shared__ float csq[128];
    int m0 = blockIdx.x * 128, n0 = blockIdx.y * 128;
    int tid = threadIdx.x;
    int lane = tid & 63, wave = tid >> 6;
    int wm = (wave & 1) * 64, wn = (wave >> 1) * 64;
    int l15 = lane & 15, l4 = lane >> 4;

    if (STATS) {
        if (tid < 128) { csum[tid] = 0.f; csq[tid] = 0.f; }
    }

    f32x4 zero = {0.f, 0.f, 0.f, 0.f};
    f32x4 acc[4][4];
#pragma unroll
    for (int i = 0; i < 4; ++i)
#pragma unroll
        for (int j = 0; j < 4; ++j) acc[i][j] = zero;

    int srow = tid >> 2;
    int scol = (tid & 3) * 8;

    int kIter = K >> 5;
    uint4 a0 = *(const uint4*)(A + (size_t)(m0 + srow) * K + scol);
    uint4 a1 = *(const uint4*)(A + (size_t)(m0 + srow + 64) * K + scol);
    uint4 b0 = *(const uint4*)(W + (size_t)(n0 + srow) * K + scol);
    uint4 b1 = *(const uint4*)(W + (size_t)(n0 + srow + 64) * K + scol);
    for (int ki = 0; ki < kIter; ++ki) {
        if (ki) __syncthreads();
        *(uint4*)&As[srow * 32 + scol] = a0;
        *(uint4*)&As[(srow + 64) * 32 + scol] = a1;
        *(uint4*)&Bs[srow * 32 + scol] = b0;
        *(uint4*)&Bs[(srow + 64) * 32 + scol] = b1;
        if (ki + 1 < kIter) {
            int k0 = (ki + 1) * 32;
            a0 = *(const uint4*)(A + (size_t)(m0 + srow) * K + k0 + scol);
            a1 = *(const uint4*)(A + (size_t)(m0 + srow + 64) * K + k0 + scol);
            b0 = *(const uint4*)(W + (size_t)(n0 + srow) * K + k0 + scol);
            b1 = *(const uint4*)(W + (size_t)(n0 + srow + 64) * K + k0 + scol);
        }
        __syncthreads();
        short8 af[4], bf[4];
#pragma unroll
        for (int t = 0; t < 4; ++t) {
            af[t] = *(const short8*)&As[(wm + t * 16 + l15) * 32 + l4 * 8];
            bf[t] = *(const short8*)&Bs[(wn + t * 16 + l15) * 32 + l4 * 8];
        }
#pragma unroll
        for (int mt = 0; mt < 4; ++mt)
#pragma unroll
            for (int nt = 0; nt < 4; ++nt)
                acc[mt][nt] = __builtin_amdgcn_mfma_f32_16x16x32_bf16(af[mt], bf[nt], acc[mt][nt], 0, 0, 0);
    }

    float ps[4] = {0.f, 0.f, 0.f, 0.f};
    float pq[4] = {0.f, 0.f, 0.f, 0.f};
    int rl = lane >> 3;
    int cg = lane & 7;
#pragma unroll
    for (int mt = 0; mt < 4; ++mt) {
#pragma unroll
        for (int nt = 0; nt < 4; ++nt) {
            int col = n0 + wn + nt * 16 + l15;
            float bs = bias[col];
#pragma unroll
            for (int r = 0; r < 4; ++r) {
                int row = m0 + wm + mt * 16 + l4 * 4 + r;
                float v = acc[mt][nt][r] + bs;
                if (RESID == 2) v += b2f(residb[(size_t)row * N + col]);
                if (RELU) v = fmaxf(v, 0.0f);
                Cs[wave][(l4 * 4 + r) * 72 + nt * 16 + l15] = f2b(v);
                if (STATS) { ps[nt] += v; pq[nt] += v * v; }
            }
        }
#pragma unroll
        for (int p = 0; p < 2; ++p) {
            int lrow = p * 8 + rl;
            uint4 wv = *(const uint4*)&Cs[wave][lrow * 72 + cg * 8];
            int grow = m0 + wm + mt * 16 + lrow;
            *(uint4*)(outb + (size_t)grow * N + n0 + wn + cg * 8) = wv;
        }
    }
    if (STATS) {
#pragma unroll
        for (int nt = 0; nt < 4; ++nt) {
            atomicAdd(&csum[wn + nt * 16 + l15], ps[nt]);
            atomicAdd(&csq[wn + nt * 16 + l15], pq[nt]);
        }
        __syncthreads();
        if (tid < 128) {
            atomicAdd(sum + n0 + tid, csum[tid]);
            atomicAdd(sumsq + n0 + tid, csq[tid]);
        }
    }
}

// ---------------- MLP1 GEMM with comb fused into A-staging; dbuf + wide stores ----------------
__global__ __launch_bounds__(256) void gemm_m1c(const u16* __restrict__ hlocb,
                                                const u16* __restrict__ t2b,
                                                const float* __restrict__ sum1,
                                                const float* __restrict__ sq1,
                                                const float* __restrict__ g1,
                                                const float* __restrict__ bt1,
                                                const float* __restrict__ sum2,
                                                const float* __restrict__ sq2,
                                                const float* __restrict__ g2,
                                                const float* __restrict__ bt2,
                                                u16* __restrict__ shb,
                                                const u16* __restrict__ Wm1b,
                                                const float* __restrict__ bm1,
                                                u16* __restrict__ hidb) {
    __shared__ u16 As[128 * 32];
    __shared__ u16 Bs[128 * 32];
    __shared__ u16 Cs[4][16 * 72];
    __shared__ float AF1[128], BF1[128], AF2[128], BF2[128];
    int tid = threadIdx.x;
    {
        int c = tid & 127;
        const float* sm = (tid < 128) ? sum1 : sum2;
        const float* sq = (tid < 128) ? sq1 : sq2;
        const float* g  = (tid < 128) ? g1 : g2;
        const float* bt = (tid < 128) ? bt1 : bt2;
        float m = sm[c] * (1.0f / NT);
        float v = sq[c] * (1.0f / NT) - m * m;
        float a = g[c] * rsqrtf(v + EPS);
        if (tid < 128) { AF1[c] = a; BF1[c] = bt[c] - m * a; }
        else           { AF2[c] = a; BF2[c] = bt[c] - m * a; }
    }
    int m0 = blockIdx.x * 128, n0 = blockIdx.y * 128;
    int lane = tid & 63, wave = tid >> 6;
    int wm = (wave & 1) * 64, wn = (wave >> 1) * 64;
    int l15 = lane & 15, l4 = lane >> 4;

    f32x4 zero = {0.f, 0.f, 0.f, 0.f};
    f32x4 acc[4][4];
#pragma unroll
    for (int i = 0; i < 4; ++i)
#pragma unroll
        for (int j = 0; j < 4; ++j) acc[i][j] = zero;

    int srow = tid >> 2;
    int scol = (tid & 3) * 8;
    bool wr = (blockIdx.y == 0);

    uint4 h0 = *(const uint4*)(hlocb + (size_t)(m0 + srow) * 128 + scol);
    uint4 h1 = *(const uint4*)(hlocb + (size_t)(m0 + srow + 64) * 128 + scol);
    uint4 t0 = *(const uint4*)(t2b + (size_t)(m0 + srow) * 128 + scol);
    uint4 t1 = *(const uint4*)(t2b + (size_t)(m0 + srow + 64) * 128 + scol);
    uint4 b0 = *(const uint4*)(Wm1b + (size_t)(n0 + srow) * 128 + scol);
    uint4 b1 = *(const uint4*)(Wm1b + (size_t)(n0 + srow + 64) * 128 + scol);
    __syncthreads();
    for (int ki = 0; ki < 4; ++ki) {
        int k0 = ki * 32;
        if (ki) __syncthreads();
        uint4 c0, c1;
        {
            const u32 hw[4] = {h0.x, h0.y, h0.z, h0.w};
            const u32 tw[4] = {t0.x, t0.y, t0.z, t0.w};
            u32 ow[4];
#pragma unroll
            for (int p = 0; p < 4; ++p) {
                int cc = k0 + scol + p * 2;
                float v0 = AF1[cc] * b2f(hw[p] & 0xffffu) + BF1[cc] + AF2[cc] * b2f(tw[p] & 0xffffu) + BF2[cc];
                float v1 = AF1[cc + 1] * b2f(hw[p] >> 16) + BF1[cc + 1] + AF2[cc + 1] * b2f(tw[p] >> 16) + BF2[cc + 1];
                ow[p] = (u32)f2b(v0) | ((u32)f2b(v1) << 16);
            }
            c0.x = ow[0]; c0.y = ow[1]; c0.z = ow[2]; c0.w = ow[3];
        }
        {
            const u32 hw[4] = {h1.x, h1.y, h1.z, h1.w};
            const u32 tw[4] = {t1.x, t1.y, t1.z, t1.w};
            u32 ow[4];
#pragma unroll
            for (int p = 0; p < 4; ++p) {
                int cc = k0 + scol + p * 2;
                float v0 = AF1[cc] * b2f(hw[p] & 0xffffu) + BF1[cc] + AF2[cc] * b2f(tw[p] & 0xffffu) + BF2[cc];
                float v1 = AF1[cc + 1] * b2f(hw[p] >> 16) + BF1[cc + 1] + AF2[cc + 1] * b2f(tw[p] >> 16) + BF2[cc + 1];
                ow[p] = (u32)f2b(v0) | ((u32)f2b(v1) << 16);
            }
            c1.x = ow[0]; c1.y = ow[1]; c1.z = ow[2]; c1.w = ow[3];
        }
        *(uint4*)&As[srow * 32 + scol] = c0;
        *(uint4*)&As[(srow + 64) * 32 + scol] = c1;
        *(uint4*)&Bs[srow * 32 + scol] = b0;
        *(uint4*)&Bs[(srow + 64) * 32 + scol] = b1;
        if (wr) {
            *(uint4*)(shb + (size_t)(m0 + srow) * 128 + k0 + scol) = c0;
            *(uint4*)(shb + (size_t)(m0 + srow + 64) * 128 + k0 + scol) = c1;
        }
        if (ki < 3) {
            int kn = k0 + 32;
            h0 = *(const uint4*)(hlocb + (size_t)(m0 + srow) * 128 + kn + scol);
            h1 = *(const uint4*)(hlocb + (size_t)(m0 + srow + 64) * 128 + kn + scol);
            t0 = *(const uint4*)(t2b + (size_t)(m0 + srow) * 128 + kn + scol);
            t1 = *(const uint4*)(t2b + (size_t)(m0 + srow + 64) * 128 + kn + scol);
            b0 = *(const uint4*)(Wm1b + (size_t)(n0 + srow) * 128 + kn + scol);
            b1 = *(const uint4*)(Wm1b + (size_t)(n0 + srow + 64) * 128 + kn + scol);
        }
        __syncthreads();
        short8 af[4], bf[4];
#pragma unroll
        for (int t = 0; t < 4; ++t) {
            af[t] = *(const short8*)&As[(wm + t * 16 + l15) * 32 + l4 * 8];
            bf[t] = *(const short8*)&Bs[(wn + t * 16 + l15) * 32 + l4 * 8];
        }
#pragma unroll
        for (int mt = 0; mt < 4; ++mt)
#pragma unroll
            for (int nt = 0; nt < 4; ++nt)
                acc[mt][nt] = __builtin_amdgcn_mfma_f32_16x16x32_bf16(af[mt], bf[nt], acc[mt][nt], 0, 0, 0);
    }

    int rl = lane >> 3;
    int cg = lane & 7;
#pragma unroll
    for (int mt = 0; mt < 4; ++mt) {
#pragma unroll
        for (int nt = 0; nt < 4; ++nt) {
            int col = n0 + wn + nt * 16 + l15;
            float bs = bm1[col];
#pragma unroll
            for (int r = 0; r < 4; ++r) {
                float v = fmaxf(acc[mt][nt][r] + bs, 0.0f);
                Cs[wave][(l4 * 4 + r) * 72 + nt * 16 + l15] = f2b(v);
            }
        }
#pragma unroll
        for (int p = 0; p < 2; ++p) {
            int lrow = p * 8 + rl;
            uint4 wv = *(const uint4*)&Cs[wave][lrow * 72 + cg * 8];
            int grow = m0 + wm + mt * 16 + lrow;
            *(uint4*)(hidb + (size_t)grow * 256 + n0 + wn + cg * 8) = wv;
        }
    }
}

// ---------------- final = bn3(out2), affine in-block, bf16 -> fp32 ----------------
__global__ __launch_bounds__(256) void final_bn(const u16* __restrict__ X,
                                                const float* __restrict__ sum3,
                                                const float* __restrict__ sq3,
                                                const float* __restrict__ g3,
                                                const float* __restrict__ bt3,
                                                float* __restrict__ outp) {
    __shared__ float A3[128], B3[128];
    int t = threadIdx.x;
    if (t < 128) {
        float m = sum3[t] * (1.0f / NT);
        float v = sq3[t] * (1.0f / NT) - m * m;
        float a = g3[t] * rsqrtf(v + EPS);
        A3[t] = a;
        B3[t] = bt3[t] - m * a;
    }
    __syncthreads();
    int i8 = blockIdx.x * 256 + t;
    size_t i = (size_t)i8 * 8;
    int c = (int)(i & (CCH - 1));
    uint4 u = *(const uint4*)(X + i);
    float x[8];
    x[0] = b2f(u.x & 0xffffu); x[1] = b2f(u.x >> 16);
    x[2] = b2f(u.y & 0xffffu); x[3] = b2f(u.y >> 16);
    x[4] = b2f(u.z & 0xffffu); x[5] = b2f(u.z >> 16);
    x[6] = b2f(u.w & 0xffffu); x[7] = b2f(u.w >> 16);
    float4 o0, o1;
    o0.x = A3[c + 0] * x[0] + B3[c + 0];
    o0.y = A3[c + 1] * x[1] + B3[c + 1];
    o0.z = A3[c + 2] * x[2] + B3[c + 2];
    o0.w = A3[c + 3] * x[3] + B3[c + 3];
    o1.x = A3[c + 4] * x[4] + B3[c + 4];
    o1.y = A3[c + 5] * x[5] + B3[c + 5];
    o1.z = A3[c + 6] * x[6] + B3[c + 6];
    o1.w = A3[c + 7] * x[7] + B3[c + 7];
    *(float4*)(outp + i) = o0;
    *(float4*)(outp + i + 4) = o1;
}

extern "C" void kernel_launch(void* const* d_in, const int* in_sizes, int n_in,
                              void* d_out, int out_size, void* d_ws, size_t ws_size,
                              hipStream_t stream) {
    const float* x    = (const float*)d_in[0];
    const int*   ei   = (const int*)d_in[1];
    const float* Wc   = (const float*)d_in[2];
    const float* bc   = (const float*)d_in[3];
    const float* Wqkv = (const float*)d_in[4];
    const float* bqkv = (const float*)d_in[5];
    const float* Wo   = (const float*)d_in[6];
    const float* bo   = (const float*)d_in[7];
    const float* gn1  = (const float*)d_in[8];
    const float* bn1b = (const float*)d_in[9];
    const float* gn2  = (const float*)d_in[10];
    const float* bn2b = (const float*)d_in[11];
    const float* gn3  = (const float*)d_in[12];
    const float* bn3b = (const float*)d_in[13];
    const float* Wm1  = (const float*)d_in[14];
    const float* bm1  = (const float*)d_in[15];
    const float* Wm2  = (const float*)d_in[16];
    const float* bm2  = (const float*)d_in[17];
    float* outp = (float*)d_out;

    char* w = (char*)d_ws;
    const size_t MB = 1024 * 1024;
    u16* xb    = (u16*)(w);                     //  8 MB
    u16* hlocb = (u16*)(w + 8 * MB);            //  8 MB
    u16* t2b   = (u16*)(w + 16 * MB);           //  8 MB  h_attn
    u16* out2b = (u16*)(w + 24 * MB);           //  8 MB
    u16* qkvb  = (u16*)(w + 32 * MB);           // 24 MB
    u16* hidb  = (u16*)(w + 56 * MB);           // 16 MB  [NT,256]
    u16* shb   = (u16*)(w + 72 * MB);           //  8 MB  agg -> comb
    u16* bucket = (u16*)(w + 80 * MB);          //  6 MB  (32768 * 96 * 2)
    int* cursor = (int*)(w + 92 * MB);          // 128 KB
    float* stats = (float*)(w + 92 * MB + 128 * 1024);   // 6*128 floats
    u16* Wcb   = (u16*)(w + 93 * MB);
    u16* Wqkvb = Wcb + 16384;
    u16* Wob   = Wqkvb + 49152;
    u16* Wm1b  = Wob + 16384;
    u16* Wm2b  = Wm1b + 32768;
    u16* ob    = (u16*)(w + 94 * MB);           //  8 MB  attention output
    float* sum1 = stats;        float* sq1 = stats + 128;
    float* sum2 = stats + 256;  float* sq2 = stats + 384;
    float* sum3 = stats + 512;  float* sq3 = stats + 640;

    hipMemsetAsync(cursor, 0, 128 * 1024 + 6 * 128 * 4, stream);

    // 1) conversions + bucket fill (fill: 4 edges/thread, u16 bucket)
    prep_kernel<<<2120 + 512, 256, 0, stream>>>(x, Wc, Wqkv, Wo, Wm1, Wm2,
                                                xb, Wcb, Wqkvb, Wob, Wm1b, Wm2b,
                                                ei, cursor, bucket);

    // 2) aggregate | QKV GEMM (independent given prep)
    stage2_kernel<<<4096 + 768, 256, 0, stream>>>(bucket, cursor, xb, shb,
                                                  Wqkvb, bqkv, qkvb);

    // 3a) attention
    attn_mfma<<<BB * NHEAD, 512, 0, stream>>>(qkvb, ob);

    // 3b) Wc GEMM (+stats1)
    {
        dim3 g(NT / 128, 1);
        gemm_mfma<false, 2, true><<<g, 256, 0, stream>>>(
            shb, Wcb, bc, xb, hlocb, sum1, sq1, NT, 128, 128);
    }

    // 4) Wo GEMM (+stats2)
    {
        dim3 g(NT / 128, 1);
        gemm_mfma<false, 2, true><<<g, 256, 0, stream>>>(
            ob, Wob, bo, xb, t2b, sum2, sq2, NT, 128, 128);
    }

    // 5) MLP1 with comb fused into staging (writes comb to shb from y==0)
    {
        dim3 g(NT / 128, 2);
        gemm_m1c<<<g, 256, 0, stream>>>(hlocb, t2b, sum1, sq1, gn1, bn1b,
                                        sum2, sq2, gn2, bn2b, shb, Wm1b, bm1, hidb);
    }

    // 6) MLP2 (+stats3)
    {
        dim3 g(NT / 128, 1);
        gemm_mfma<false, 2, true><<<g, 256, 0, stream>>>(
            hidb, Wm2b, bm2, shb, out2b, sum3, sq3, NT, 128, 256);
    }

    // 7) final BN
    final_bn<<<NT * CCH / 8 / 256, 256, 0, stream>>>(out2b, sum3, sq3, gn3, bn3b, outp);
}

// Round 13
// 252.673 us; speedup vs baseline: 1.0304x; 1.0304x over previous
//
#include <hip/hip_runtime.h>
#include <cstddef>

#define NT    32768
#define CCH   128
#define BB    64
#define NNODE 512
#define NHEAD 4
#define DHEAD 32
#define EE    524288
#define EPS   1e-5f
#define MAXDEG 96
#define VTS   524

typedef unsigned short u16;
typedef unsigned int   u32;
typedef __attribute__((ext_vector_type(8))) short short8;
typedef __attribute__((ext_vector_type(4))) short short4v;
typedef __attribute__((ext_vector_type(4))) float f32x4;

__device__ __forceinline__ float b2f(u32 w) { return __uint_as_float(w << 16); }
__device__ __forceinline__ u16 f2b(float f) {
    u32 u = __float_as_uint(f);
    u += 0x7FFF + ((u >> 16) & 1);   // RNE
    return (u16)(u >> 16);
}

// ---------------- convert: fp32 -> bf16 (x + 5 weights), 2120 blocks ----------------
__global__ __launch_bounds__(256) void convert_kernel(const float* __restrict__ x,
                                                      const float* __restrict__ Wc,
                                                      const float* __restrict__ Wqkv,
                                                      const float* __restrict__ Wo,
                                                      const float* __restrict__ Wm1,
                                                      const float* __restrict__ Wm2,
                                                      u16* __restrict__ xb,
                                                      u16* __restrict__ Wcb,
                                                      u16* __restrict__ Wqkvb,
                                                      u16* __restrict__ Wob,
                                                      u16* __restrict__ Wm1b,
                                                      u16* __restrict__ Wm2b) {
    int r = blockIdx.x * 256 + threadIdx.x;
    const float* src; u16* dst;
    if (r < 524288) { src = x; dst = xb; }
    else if ((r -= 524288) < 2048) { src = Wc; dst = Wcb; }
    else if ((r -= 2048) < 6144) { src = Wqkv; dst = Wqkvb; }
    else if ((r -= 6144) < 2048) { src = Wo; dst = Wob; }
    else if ((r -= 2048) < 4096) { src = Wm1; dst = Wm1b; }
    else { r -= 4096; src = Wm2; dst = Wm2b; }
    size_t base = (size_t)r * 8;
    float4 a = *(const float4*)(src + base);
    float4 b = *(const float4*)(src + base + 4);
    uint4 u;
    u.x = (u32)f2b(a.x) | ((u32)f2b(a.y) << 16);
    u.y = (u32)f2b(a.z) | ((u32)f2b(a.w) << 16);
    u.z = (u32)f2b(b.x) | ((u32)f2b(b.y) << 16);
    u.w = (u32)f2b(b.z) | ((u32)f2b(b.w) << 16);
    *(uint4*)(dst + base) = u;
}

// ---------------- K2: QKV GEMM (blocks 0..767) | bucket fill (blocks 768..1279) ----------------
// fill is atomic-fabric-bound (waves mostly waiting); QKV keeps the CUs busy.
__global__ __launch_bounds__(256) void fill_qkv_kernel(const int* __restrict__ ei,
                                                       int* __restrict__ cursor,
                                                       u16* __restrict__ bucket,
                                                       const u16* __restrict__ xb,
                                                       const u16* __restrict__ Wqkvb,
                                                       const float* __restrict__ bqkv,
                                                       u16* __restrict__ qkvb) {
    __shared__ __align__(16) char smem[25600];
    int tid = threadIdx.x;
    if (blockIdx.x >= 768) {
        int t = (blockIdx.x - 768) * 256 + tid;
        int e = t * 4;
        int4 sv = *(const int4*)(ei + e);
        int4 dv = *(const int4*)(ei + EE + e);
        int p0 = atomicAdd(cursor + dv.x, 1);
        int p1 = atomicAdd(cursor + dv.y, 1);
        int p2 = atomicAdd(cursor + dv.z, 1);
        int p3 = atomicAdd(cursor + dv.w, 1);
        if (p0 < MAXDEG) bucket[dv.x * MAXDEG + p0] = (u16)sv.x;
        if (p1 < MAXDEG) bucket[dv.y * MAXDEG + p1] = (u16)sv.y;
        if (p2 < MAXDEG) bucket[dv.z * MAXDEG + p2] = (u16)sv.z;
        if (p3 < MAXDEG) bucket[dv.w * MAXDEG + p3] = (u16)sv.w;
        return;
    }
    int bx = blockIdx.x;
    int y = bx >> 8;
    int m0 = (bx & 255) * 128;
    const u16* W = Wqkvb + (size_t)y * 128 * 128;
    const float* bias = bqkv + y * 128;
    u16* As = (u16*)smem;                 // 8192 B
    u16* Bs = (u16*)(smem + 8192);        // 8192 B
    u16* Cs = (u16*)(smem + 16384);       // 9216 B

    int lane = tid & 63, wave = tid >> 6;
    int wm = (wave & 1) * 64, wn = (wave >> 1) * 64;
    int l15 = lane & 15, l4 = lane >> 4;

    f32x4 zero = {0.f, 0.f, 0.f, 0.f};
    f32x4 acc[4][4];
#pragma unroll
    for (int i = 0; i < 4; ++i)
#pragma unroll
        for (int j = 0; j < 4; ++j) acc[i][j] = zero;

    int srow = tid >> 2;
    int scol = (tid & 3) * 8;

    uint4 a0 = *(const uint4*)(xb + (size_t)(m0 + srow) * 128 + scol);
    uint4 a1 = *(const uint4*)(xb + (size_t)(m0 + srow + 64) * 128 + scol);
    uint4 b0 = *(const uint4*)(W + (size_t)srow * 128 + scol);
    uint4 b1 = *(const uint4*)(W + (size_t)(srow + 64) * 128 + scol);
    for (int ki = 0; ki < 4; ++ki) {
        if (ki) __syncthreads();
        *(uint4*)&As[srow * 32 + scol] = a0;
        *(uint4*)&As[(srow + 64) * 32 + scol] = a1;
        *(uint4*)&Bs[srow * 32 + scol] = b0;
        *(uint4*)&Bs[(srow + 64) * 32 + scol] = b1;
        if (ki < 3) {
            int k0 = (ki + 1) * 32;
            a0 = *(const uint4*)(xb + (size_t)(m0 + srow) * 128 + k0 + scol);
            a1 = *(const uint4*)(xb + (size_t)(m0 + srow + 64) * 128 + k0 + scol);
            b0 = *(const uint4*)(W + (size_t)srow * 128 + k0 + scol);
            b1 = *(const uint4*)(W + (size_t)(srow + 64) * 128 + k0 + scol);
        }
        __syncthreads();
        short8 af[4], bf[4];
#pragma unroll
        for (int t = 0; t < 4; ++t) {
            af[t] = *(const short8*)&As[(wm + t * 16 + l15) * 32 + l4 * 8];
            bf[t] = *(const short8*)&Bs[(wn + t * 16 + l15) * 32 + l4 * 8];
        }
#pragma unroll
        for (int mt = 0; mt < 4; ++mt)
#pragma unroll
            for (int nt = 0; nt < 4; ++nt)
                acc[mt][nt] = __builtin_amdgcn_mfma_f32_16x16x32_bf16(af[mt], bf[nt], acc[mt][nt], 0, 0, 0);
    }

    int rl = lane >> 3;
    int cg = lane & 7;
    u16* Cw = Cs + wave * 16 * 72;
#pragma unroll
    for (int mt = 0; mt < 4; ++mt) {
#pragma unroll
        for (int nt = 0; nt < 4; ++nt) {
            float bs = bias[wn + nt * 16 + l15];
#pragma unroll
            for (int r = 0; r < 4; ++r)
                Cw[(l4 * 4 + r) * 72 + nt * 16 + l15] = f2b(acc[mt][nt][r] + bs);
        }
#pragma unroll
        for (int p = 0; p < 2; ++p) {
            int lrow = p * 8 + rl;
            uint4 wv = *(const uint4*)&Cw[lrow * 72 + cg * 8];
            int grow = m0 + wm + mt * 16 + lrow;
            *(uint4*)(qkvb + (size_t)grow * 384 + y * 128 + wn + cg * 8) = wv;
        }
    }
}

// ---------------- K3: attention (blocks 0..255) | aggregate (blocks 256..2303), 512 threads ----------------
// Both halves are latency-bound; LDS-capped occupancy (2 blocks/CU) is fine for each.
__global__ __launch_bounds__(512) void agg_attn_kernel(const u16* __restrict__ qkvb,
                                                       u16* __restrict__ ob,
                                                       const u16* __restrict__ bucket,
                                                       const int* __restrict__ cursor,
                                                       const u16* __restrict__ xb,
                                                       u16* __restrict__ aggb) {
    __shared__ __align__(16) char smem[74496];
    int tid = threadIdx.x;
    if (blockIdx.x >= 256) {
        // ---- gather-mean aggregation: 16 nodes/block ----
        int* srcs = (int*)smem;              // [16][96] = 6144 B
        int ln = tid >> 5;                   // 0..15
        int c4 = tid & 31;
        int n = (blockIdx.x - 256) * 16 + ln;
        int d = min(cursor[n], MAXDEG);
        for (int j = c4; j < d; j += 32) srcs[ln * MAXDEG + j] = bucket[n * MAXDEG + j];
        __syncthreads();
        float s0 = 0.f, s1 = 0.f, s2 = 0.f, s3 = 0.f;
        for (int j = 0; j < d; ++j) {
            uint2 w = *(const uint2*)(xb + (size_t)srcs[ln * MAXDEG + j] * CCH + c4 * 4);
            s0 += b2f(w.x & 0xffffu);
            s1 += b2f(w.x >> 16);
            s2 += b2f(w.y & 0xffffu);
            s3 += b2f(w.y >> 16);
        }
        float inv = 1.0f / fmaxf((float)d, 1.0f);
        uint2 out;
        out.x = (u32)f2b(s0 * inv) | ((u32)f2b(s1 * inv) << 16);
        out.y = (u32)f2b(s2 * inv) | ((u32)f2b(s3 * inv) << 16);
        *(uint2*)(aggb + (size_t)n * CCH + c4 * 4) = out;
        return;
    }
    // ---- MFMA flash attention, S^T chained, 8 waves x 4 q-tiles ----
    u16* Ks = (u16*)smem;                    // 512*40*2 = 40960 B
    u16* Vt = (u16*)(smem + 40960);          // 32*524*2 = 33536 B
    int bh = blockIdx.x;
    int b = bh >> 2, h = bh & 3;
    int lane = tid & 63, wave = tid >> 6;
    int quad = lane >> 4, l15 = lane & 15;
    const float scale = 0.1767766952966369f;  // 1/sqrt(32)

    const u16* kvbase = qkvb + (size_t)b * 512 * 384 + 128 + h * 32;
    for (int idx = tid; idx < 2048; idx += 512) {
        int row = idx >> 2, c = idx & 3;
        *(uint4*)&Ks[row * 40 + c * 8] = *(const uint4*)(kvbase + (size_t)row * 384 + c * 8);
    }
    for (int idx = tid; idx < 2048; idx += 512) {
        int row = idx >> 2, c = idx & 3;
        uint4 u = *(const uint4*)(kvbase + 128 + (size_t)row * 384 + c * 8);
        u16 e[8];
        *(uint4*)e = u;
#pragma unroll
        for (int i = 0; i < 8; ++i) Vt[(c * 8 + i) * VTS + row] = e[i];
    }
    __syncthreads();

    f32x4 zero = {0.f, 0.f, 0.f, 0.f};
    for (int qt = 0; qt < 4; ++qt) {
        int qbase = wave * 64 + qt * 16;
        short8 qf = *(const short8*)(qkvb + (size_t)(b * 512 + qbase + l15) * 384 + h * 32 + quad * 8);
        float lq = 0.f;
        f32x4 oa[2] = {zero, zero};

        for (int kv0 = 0; kv0 < 512; kv0 += 64) {
            f32x4 s[4];
#pragma unroll
            for (int t = 0; t < 4; ++t) {
                short8 kb = *(const short8*)&Ks[(kv0 + t * 16 + l15) * 40 + quad * 8];
                s[t] = __builtin_amdgcn_mfma_f32_16x16x32_bf16(kb, qf, zero, 0, 0, 0);
            }
            short8 pa[4];
#pragma unroll
            for (int t = 0; t < 4; ++t) {
                float p0 = __expf(s[t][0] * scale);
                float p1 = __expf(s[t][1] * scale);
                float p2 = __expf(s[t][2] * scale);
                float p3 = __expf(s[t][3] * scale);
                lq += (p0 + p1) + (p2 + p3);
                short8 a8 = {(short)f2b(p0), (short)f2b(p1), (short)f2b(p2), (short)f2b(p3), 0, 0, 0, 0};
                pa[t] = a8;
            }
#pragma unroll
            for (int t = 0; t < 4; ++t) {
                int tbase = kv0 + t * 16;
#pragma unroll
                for (int n = 0; n < 2; ++n) {
                    short4v v4 = *(const short4v*)&Vt[(n * 16 + l15) * VTS + tbase + quad * 4];
                    short8 vb = {v4.x, v4.y, v4.z, v4.w, 0, 0, 0, 0};
                    oa[n] = __builtin_amdgcn_mfma_f32_16x16x32_bf16(pa[t], vb, oa[n], 0, 0, 0);
                }
            }
        }
        lq += __shfl_xor(lq, 16);
        lq += __shfl_xor(lq, 32);
        u16* op = ob + (size_t)(b * 512 + qbase) * 128 + h * 32;
#pragma unroll
        for (int r = 0; r < 4; ++r) {
            float Lr = __shfl(lq, quad * 4 + r);
            float inv = 1.0f / Lr;
#pragma unroll
            for (int n = 0; n < 2; ++n)
                op[(quad * 4 + r) * 128 + n * 16 + l15] = f2b(oa[n][r] * inv);
        }
    }
}

// ---------------- K4: Wc GEMM (y=0) | Wo GEMM (y=1) — both K=128, resid=xb, stats ----------------
__global__ __launch_bounds__(256) void gemm_wcwo(const u16* __restrict__ aggb,
                                                 const u16* __restrict__ ob,
                                                 const u16* __restrict__ Wcb,
                                                 const u16* __restrict__ Wob,
                                                 const float* __restrict__ bc,
                                                 const float* __restrict__ bo,
                                                 const u16* __restrict__ xb,
                                                 u16* __restrict__ hlocb,
                                                 u16* __restrict__ t2b,
                                                 float* __restrict__ sum1,
                                                 float* __restrict__ sq1,
                                                 float* __restrict__ sum2,
                                                 float* __restrict__ sq2) {
    __shared__ u16 As[128 * 32];
    __shared__ u16 Bs[128 * 32];
    __shared__ u16 Cs[4][16 * 72];
    __shared__ float csum[128];
    __shared__ float csq[128];
    int y = blockIdx.y;
    const u16* A = y ? ob : aggb;
    const u16* W = y ? Wob : Wcb;
    const float* bias = y ? bo : bc;
    u16* outb = y ? t2b : hlocb;
    float* sum = y ? sum2 : sum1;
    float* sumsq = y ? sq2 : sq1;

    int m0 = blockIdx.x * 128;
    int tid = threadIdx.x;
    int lane = tid & 63, wave = tid >> 6;
    int wm = (wave & 1) * 64, wn = (wave >> 1) * 64;
    int l15 = lane & 15, l4 = lane >> 4;

    if (tid < 128) { csum[tid] = 0.f; csq[tid] = 0.f; }

    f32x4 zero = {0.f, 0.f, 0.f, 0.f};
    f32x4 acc[4][4];
#pragma unroll
    for (int i = 0; i < 4; ++i)
#pragma unroll
        for (int j = 0; j < 4; ++j) acc[i][j] = zero;

    int srow = tid >> 2;
    int scol = (tid & 3) * 8;

    uint4 a0 = *(const uint4*)(A + (size_t)(m0 + srow) * 128 + scol);
    uint4 a1 = *(const uint4*)(A + (size_t)(m0 + srow + 64) * 128 + scol);
    uint4 b0 = *(const uint4*)(W + (size_t)srow * 128 + scol);
    uint4 b1 = *(const uint4*)(W + (size_t)(srow + 64) * 128 + scol);
    for (int ki = 0; ki < 4; ++ki) {
        if (ki) __syncthreads();
        *(uint4*)&As[srow * 32 + scol] = a0;
        *(uint4*)&As[(srow + 64) * 32 + scol] = a1;
        *(uint4*)&Bs[srow * 32 + scol] = b0;
        *(uint4*)&Bs[(srow + 64) * 32 + scol] = b1;
        if (ki < 3) {
            int k0 = (ki + 1) * 32;
            a0 = *(const uint4*)(A + (size_t)(m0 + srow) * 128 + k0 + scol);
            a1 = *(const uint4*)(A + (size_t)(m0 + srow + 64) * 128 + k0 + scol);
            b0 = *(const uint4*)(W + (size_t)srow * 128 + k0 + scol);
            b1 = *(const uint4*)(W + (size_t)(srow + 64) * 128 + k0 + scol);
        }
        __syncthreads();
        short8 af[4], bf[4];
#pragma unroll
        for (int t = 0; t < 4; ++t) {
            af[t] = *(const short8*)&As[(wm + t * 16 + l15) * 32 + l4 * 8];
            bf[t] = *(const short8*)&Bs[(wn + t * 16 + l15) * 32 + l4 * 8];
        }
#pragma unroll
        for (int mt = 0; mt < 4; ++mt)
#pragma unroll
            for (int nt = 0; nt < 4; ++nt)
                acc[mt][nt] = __builtin_amdgcn_mfma_f32_16x16x32_bf16(af[mt], bf[nt], acc[mt][nt], 0, 0, 0);
    }

    float ps[4] = {0.f, 0.f, 0.f, 0.f};
    float pq[4] = {0.f, 0.f, 0.f, 0.f};
    int rl = lane >> 3;
    int cg = lane & 7;
#pragma unroll
    for (int mt = 0; mt < 4; ++mt) {
#pragma unroll
        for (int nt = 0; nt < 4; ++nt) {
            int lcol = wn + nt * 16 + l15;
            float bs = bias[lcol];
#pragma unroll
            for (int r = 0; r < 4; ++r) {
                int row = m0 + wm + mt * 16 + l4 * 4 + r;
                float v = acc[mt][nt][r] + bs + b2f(xb[(size_t)row * 128 + lcol]);
                Cs[wave][(l4 * 4 + r) * 72 + nt * 16 + l15] = f2b(v);
                ps[nt] += v; pq[nt] += v * v;
            }
        }
#pragma unroll
        for (int p = 0; p < 2; ++p) {
            int lrow = p * 8 + rl;
            uint4 wv = *(const uint4*)&Cs[wave][lrow * 72 + cg * 8];
            int grow = m0 + wm + mt * 16 + lrow;
            *(uint4*)(outb + (size_t)grow * 128 + wn + cg * 8) = wv;
        }
    }
#pragma unroll
    for (int nt = 0; nt < 4; ++nt) {
        atomicAdd(&csum[wn + nt * 16 + l15], ps[nt]);
        atomicAdd(&csq[wn + nt * 16 + l15], pq[nt]);
    }
    __syncthreads();
    if (tid < 128) {
        atomicAdd(sum + tid, csum[tid]);
        atomicAdd(sumsq + tid, csq[tid]);
    }
}

// ---------------- bf16 MFMA GEMM (MLP2): dbuf + wide-store epilogue ----------------
template <bool RELU, int RESID, bool STATS>
__global__ __launch_bounds__(256) void gemm_mfma(const u16* __restrict__ A,
                                                 const u16* __restrict__ W,
                                                 const float* __restrict__ bias,
                                                 const u16* __restrict__ residb,
                                                 u16* __restrict__ outb,
                                                 float* __restrict__ sum,
                                                 float* __restrict__ sumsq,
                                                 int M, int N, int K) {
    __shared__ u16 As[128 * 32];
    __shared__ u16 Bs[128 * 32];
    __shared__ u16 Cs[4][16 * 72];
    __shared__ float csum[128];
    __shared__ float csq[128];
    int m0 = blockIdx.x * 128, n0 = blockIdx.y * 128;
    int tid = threadIdx.x;
    int lane = tid & 63, wave = tid >> 6;
    int wm = (wave & 1) * 64, wn = (wave >> 1) * 64;
    int l15 = lane & 15, l4 = lane >> 4;

    if (STATS) {
        if (tid < 128) { csum[tid] = 0.f; csq[tid] = 0.f; }
    }

    f32x4 zero = {0.f, 0.f, 0.f, 0.f};
    f32x4 acc[4][4];
#pragma unroll
    for (int i = 0; i < 4; ++i)
#pragma unroll
        for (int j = 0; j < 4; ++j) acc[i][j] = zero;

    int srow = tid >> 2;
    int scol = (tid & 3) * 8;

    int kIter = K >> 5;
    uint4 a0 = *(const uint4*)(A + (size_t)(m0 + srow) * K + scol);
    uint4 a1 = *(const uint4*)(A + (size_t)(m0 + srow + 64) * K + scol);
    uint4 b0 = *(const uint4*)(W + (size_t)(n0 + srow) * K + scol);
    uint4 b1 = *(const uint4*)(W + (size_t)(n0 + srow + 64) * K + scol);
    for (int ki = 0; ki < kIter; ++ki) {
        if (ki) __syncthreads();
        *(uint4*)&As[srow * 32 + scol] = a0;
        *(uint4*)&As[(srow + 64) * 32 + scol] = a1;
        *(uint4*)&Bs[srow * 32 + scol] = b0;
        *(uint4*)&Bs[(srow + 64) * 32 + scol] = b1;
        if (ki + 1 < kIter) {
            int k0 = (ki + 1) * 32;
            a0 = *(const uint4*)(A + (size_t)(m0 + srow) * K + k0 + scol);
            a1 = *(const uint4*)(A + (size_t)(m0 + srow + 64) * K + k0 + scol);
            b0 = *(const uint4*)(W + (size_t)(n0 + srow) * K + k0 + scol);
            b1 = *(const uint4*)(W + (size_t)(n0 + srow + 64) * K + k0 + scol);
        }
        __syncthreads();
        short8 af[4], bf[4];
#pragma unroll
        for (int t = 0; t < 4; ++t) {
            af[t] = *(const short8*)&As[(wm + t * 16 + l15) * 32 + l4 * 8];
            bf[t] = *(const short8*)&Bs[(wn + t * 16 + l15) * 32 + l4 * 8];
        }
#pragma unroll
        for (int mt = 0; mt < 4; ++mt)
#pragma unroll
            for (int nt = 0; nt < 4; ++nt)
                acc[mt][nt] = __builtin_amdgcn_mfma_f32_16x16x32_bf16(af[mt], bf[nt], acc[mt][nt], 0, 0, 0);
    }

    float ps[4] = {0.f, 0.f, 0.f, 0.f};
    float pq[4] = {0.f, 0.f, 0.f, 0.f};
    int rl = lane >> 3;
    int cg = lane & 7;
#pragma unroll
    for (int mt = 0; mt < 4; ++mt) {
#pragma unroll
        for (int nt = 0; nt < 4; ++nt) {
            int col = n0 + wn + nt * 16 + l15;
            float bs = bias[col];
#pragma unroll
            for (int r = 0; r < 4; ++r) {
                int row = m0 + wm + mt * 16 + l4 * 4 + r;
                float v = acc[mt][nt][r] + bs;
                if (RESID == 2) v += b2f(residb[(size_t)row * N + col]);
                if (RELU) v = fmaxf(v, 0.0f);
                Cs[wave][(l4 * 4 + r) * 72 + nt * 16 + l15] = f2b(v);
                if (STATS) { ps[nt] += v; pq[nt] += v * v; }
            }
        }
#pragma unroll
        for (int p = 0; p < 2; ++p) {
            int lrow = p * 8 + rl;
            uint4 wv = *(const uint4*)&Cs[wave][lrow * 72 + cg * 8];
            int grow = m0 + wm + mt * 16 + lrow;
            *(uint4*)(outb + (size_t)grow * N + n0 + wn + cg * 8) = wv;
        }
    }
    if (STATS) {
#pragma unroll
        for (int nt = 0; nt < 4; ++nt) {
            atomicAdd(&csum[wn + nt * 16 + l15], ps[nt]);
            atomicAdd(&csq[wn + nt * 16 + l15], pq[nt]);
        }
        __syncthreads();
        if (tid < 128) {
            atomicAdd(sum + n0 + tid, csum[tid]);
            atomicAdd(sumsq + n0 + tid, csq[tid]);
        }
    }
}

// ---------------- MLP1 GEMM with comb fused into A-staging; dbuf + wide stores ----------------
__global__ __launch_bounds__(256) void gemm_m1c(const u16* __restrict__ hlocb,
                                                const u16* __restrict__ t2b,
                                                const float* __restrict__ sum1,
                                                const float* __restrict__ sq1,
                                                const float* __restrict__ g1,
                                                const float* __restrict__ bt1,
                                                const float* __restrict__ sum2,
                                                const float* __restrict__ sq2,
                                                const float* __restrict__ g2,
                                                const float* __restrict__ bt2,
                                                u16* __restrict__ shb,
                                                const u16* __restrict__ Wm1b,
                                                const float* __restrict__ bm1,
                                                u16* __restrict__ hidb) {
    __shared__ u16 As[128 * 32];
    __shared__ u16 Bs[128 * 32];
    __shared__ u16 Cs[4][16 * 72];
    __shared__ float AF1[128], BF1[128], AF2[128], BF2[128];
    int tid = threadIdx.x;
    {
        int c = tid & 127;
        const float* sm = (tid < 128) ? sum1 : sum2;
        const float* sq = (tid < 128) ? sq1 : sq2;
        const float* g  = (tid < 128) ? g1 : g2;
        const float* bt = (tid < 128) ? bt1 : bt2;
        float m = sm[c] * (1.0f / NT);
        float v = sq[c] * (1.0f / NT) - m * m;
        float a = g[c] * rsqrtf(v + EPS);
        if (tid < 128) { AF1[c] = a; BF1[c] = bt[c] - m * a; }
        else           { AF2[c] = a; BF2[c] = bt[c] - m * a; }
    }
    int m0 = blockIdx.x * 128, n0 = blockIdx.y * 128;
    int lane = tid & 63, wave = tid >> 6;
    int wm = (wave & 1) * 64, wn = (wave >> 1) * 64;
    int l15 = lane & 15, l4 = lane >> 4;

    f32x4 zero = {0.f, 0.f, 0.f, 0.f};
    f32x4 acc[4][4];
#pragma unroll
    for (int i = 0; i < 4; ++i)
#pragma unroll
        for (int j = 0; j < 4; ++j) acc[i][j] = zero;

    int srow = tid >> 2;
    int scol = (tid & 3) * 8;
    bool wr = (blockIdx.y == 0);

    uint4 h0 = *(const uint4*)(hlocb + (size_t)(m0 + srow) * 128 + scol);
    uint4 h1 = *(const uint4*)(hlocb + (size_t)(m0 + srow + 64) * 128 + scol);
    uint4 t0 = *(const uint4*)(t2b + (size_t)(m0 + srow) * 128 + scol);
    uint4 t1 = *(const uint4*)(t2b + (size_t)(m0 + srow + 64) * 128 + scol);
    uint4 b0 = *(const uint4*)(Wm1b + (size_t)(n0 + srow) * 128 + scol);
    uint4 b1 = *(const uint4*)(Wm1b + (size_t)(n0 + srow + 64) * 128 + scol);
    __syncthreads();
    for (int ki = 0; ki < 4; ++ki) {
        int k0 = ki * 32;
        if (ki) __syncthreads();
        uint4 c0, c1;
        {
            const u32 hw[4] = {h0.x, h0.y, h0.z, h0.w};
            const u32 tw[4] = {t0.x, t0.y, t0.z, t0.w};
            u32 ow[4];
#pragma unroll
            for (int p = 0; p < 4; ++p) {
                int cc = k0 + scol + p * 2;
                float v0 = AF1[cc] * b2f(hw[p] & 0xffffu) + BF1[cc] + AF2[cc] * b2f(tw[p] & 0xffffu) + BF2[cc];
                float v1 = AF1[cc + 1] * b2f(hw[p] >> 16) + BF1[cc + 1] + AF2[cc + 1] * b2f(tw[p] >> 16) + BF2[cc + 1];
                ow[p] = (u32)f2b(v0) | ((u32)f2b(v1) << 16);
            }
            c0.x = ow[0]; c0.y = ow[1]; c0.z = ow[2]; c0.w = ow[3];
        }
        {
            const u32 hw[4] = {h1.x, h1.y, h1.z, h1.w};
            const u32 tw[4] = {t1.x, t1.y, t1.z, t1.w};
            u32 ow[4];
#pragma unroll
            for (int p = 0; p < 4; ++p) {
                int cc = k0 + scol + p * 2;
                float v0 = AF1[cc] * b2f(hw[p] & 0xffffu) + BF1[cc] + AF2[cc] * b2f(tw[p] & 0xffffu) + BF2[cc];
                float v1 = AF1[cc + 1] * b2f(hw[p] >> 16) + BF1[cc + 1] + AF2[cc + 1] * b2f(tw[p] >> 16) + BF2[cc + 1];
                ow[p] = (u32)f2b(v0) | ((u32)f2b(v1) << 16);
            }
            c1.x = ow[0]; c1.y = ow[1]; c1.z = ow[2]; c1.w = ow[3];
        }
        *(uint4*)&As[srow * 32 + scol] = c0;
        *(uint4*)&As[(srow + 64) * 32 + scol] = c1;
        *(uint4*)&Bs[srow * 32 + scol] = b0;
        *(uint4*)&Bs[(srow + 64) * 32 + scol] = b1;
        if (wr) {
            *(uint4*)(shb + (size_t)(m0 + srow) * 128 + k0 + scol) = c0;
            *(uint4*)(shb + (size_t)(m0 + srow + 64) * 128 + k0 + scol) = c1;
        }
        if (ki < 3) {
            int kn = k0 + 32;
            h0 = *(const uint4*)(hlocb + (size_t)(m0 + srow) * 128 + kn + scol);
            h1 = *(const uint4*)(hlocb + (size_t)(m0 + srow + 64) * 128 + kn + scol);
            t0 = *(const uint4*)(t2b + (size_t)(m0 + srow) * 128 + kn + scol);
            t1 = *(const uint4*)(t2b + (size_t)(m0 + srow + 64) * 128 + kn + scol);
            b0 = *(const uint4*)(Wm1b + (size_t)(n0 + srow) * 128 + kn + scol);
            b1 = *(const uint4*)(Wm1b + (size_t)(n0 + srow + 64) * 128 + kn + scol);
        }
        __syncthreads();
        short8 af[4], bf[4];
#pragma unroll
        for (int t = 0; t < 4; ++t) {
            af[t] = *(const short8*)&As[(wm + t * 16 + l15) * 32 + l4 * 8];
            bf[t] = *(const short8*)&Bs[(wn + t * 16 + l15) * 32 + l4 * 8];
        }
#pragma unroll
        for (int mt = 0; mt < 4; ++mt)
#pragma unroll
            for (int nt = 0; nt < 4; ++nt)
                acc[mt][nt] = __builtin_amdgcn_mfma_f32_16x16x32_bf16(af[mt], bf[nt], acc[mt][nt], 0, 0, 0);
    }

    int rl = lane >> 3;
    int cg = lane & 7;
#pragma unroll
    for (int mt = 0; mt < 4; ++mt) {
#pragma unroll
        for (int nt = 0; nt < 4; ++nt) {
            int col = n0 + wn + nt * 16 + l15;
            float bs = bm1[col];
#pragma unroll
            for (int r = 0; r < 4; ++r) {
                float v = fmaxf(acc[mt][nt][r] + bs, 0.0f);
                Cs[wave][(l4 * 4 + r) * 72 + nt * 16 + l15] = f2b(v);
            }
        }
#pragma unroll
        for (int p = 0; p < 2; ++p) {
            int lrow = p * 8 + rl;
            uint4 wv = *(const uint4*)&Cs[wave][lrow * 72 + cg * 8];
            int grow = m0 + wm + mt * 16 + lrow;
            *(uint4*)(hidb + (size_t)grow * 256 + n0 + wn + cg * 8) = wv;
        }
    }
}

// ---------------- final = bn3(out2), affine in-block, bf16 -> fp32 ----------------
__global__ __launch_bounds__(256) void final_bn(const u16* __restrict__ X,
                                                const float* __restrict__ sum3,
                                                const float* __restrict__ sq3,
                                                const float* __restrict__ g3,
                                                const float* __restrict__ bt3,
                                                float* __restrict__ outp) {
    __shared__ float A3[128], B3[128];
    int t = threadIdx.x;
    if (t < 128) {
        float m = sum3[t] * (1.0f / NT);
        float v = sq3[t] * (1.0f / NT) - m * m;
        float a = g3[t] * rsqrtf(v + EPS);
        A3[t] = a;
        B3[t] = bt3[t] - m * a;
    }
    __syncthreads();
    int i8 = blockIdx.x * 256 + t;
    size_t i = (size_t)i8 * 8;
    int c = (int)(i & (CCH - 1));
    uint4 u = *(const uint4*)(X + i);
    float x[8];
    x[0] = b2f(u.x & 0xffffu); x[1] = b2f(u.x >> 16);
    x[2] = b2f(u.y & 0xffffu); x[3] = b2f(u.y >> 16);
    x[4] = b2f(u.z & 0xffffu); x[5] = b2f(u.z >> 16);
    x[6] = b2f(u.w & 0xffffu); x[7] = b2f(u.w >> 16);
    float4 o0, o1;
    o0.x = A3[c + 0] * x[0] + B3[c + 0];
    o0.y = A3[c + 1] * x[1] + B3[c + 1];
    o0.z = A3[c + 2] * x[2] + B3[c + 2];
    o0.w = A3[c + 3] * x[3] + B3[c + 3];
    o1.x = A3[c + 4] * x[4] + B3[c + 4];
    o1.y = A3[c + 5] * x[5] + B3[c + 5];
    o1.z = A3[c + 6] * x[6] + B3[c + 6];
    o1.w = A3[c + 7] * x[7] + B3[c + 7];
    *(float4*)(outp + i) = o0;
    *(float4*)(outp + i + 4) = o1;
}

extern "C" void kernel_launch(void* const* d_in, const int* in_sizes, int n_in,
                              void* d_out, int out_size, void* d_ws, size_t ws_size,
                              hipStream_t stream) {
    const float* x    = (const float*)d_in[0];
    const int*   ei   = (const int*)d_in[1];
    const float* Wc   = (const float*)d_in[2];
    const float* bc   = (const float*)d_in[3];
    const float* Wqkv = (const float*)d_in[4];
    const float* bqkv = (const float*)d_in[5];
    const float* Wo   = (const float*)d_in[6];
    const float* bo   = (const float*)d_in[7];
    const float* gn1  = (const float*)d_in[8];
    const float* bn1b = (const float*)d_in[9];
    const float* gn2  = (const float*)d_in[10];
    const float* bn2b = (const float*)d_in[11];
    const float* gn3  = (const float*)d_in[12];
    const float* bn3b = (const float*)d_in[13];
    const float* Wm1  = (const float*)d_in[14];
    const float* bm1  = (const float*)d_in[15];
    const float* Wm2  = (const float*)d_in[16];
    const float* bm2  = (const float*)d_in[17];
    float* outp = (float*)d_out;

    char* w = (char*)d_ws;
    const size_t MB = 1024 * 1024;
    u16* xb    = (u16*)(w);                     //  8 MB
    u16* hlocb = (u16*)(w + 8 * MB);            //  8 MB
    u16* t2b   = (u16*)(w + 16 * MB);           //  8 MB  h_attn
    u16* out2b = (u16*)(w + 24 * MB);           //  8 MB
    u16* qkvb  = (u16*)(w + 32 * MB);           // 24 MB
    u16* hidb  = (u16*)(w + 56 * MB);           // 16 MB  [NT,256]
    u16* shb   = (u16*)(w + 72 * MB);           //  8 MB  agg -> comb
    u16* bucket = (u16*)(w + 80 * MB);          //  6 MB
    int* cursor = (int*)(w + 92 * MB);          // 128 KB
    float* stats = (float*)(w + 92 * MB + 128 * 1024);
    u16* Wcb   = (u16*)(w + 93 * MB);
    u16* Wqkvb = Wcb + 16384;
    u16* Wob   = Wqkvb + 49152;
    u16* Wm1b  = Wob + 16384;
    u16* Wm2b  = Wm1b + 32768;
    u16* ob    = (u16*)(w + 94 * MB);           //  8 MB  attention output
    float* sum1 = stats;        float* sq1 = stats + 128;
    float* sum2 = stats + 256;  float* sq2 = stats + 384;
    float* sum3 = stats + 512;  float* sq3 = stats + 640;

    hipMemsetAsync(cursor, 0, 128 * 1024 + 6 * 128 * 4, stream);

    // K1) conversions
    convert_kernel<<<2120, 256, 0, stream>>>(x, Wc, Wqkv, Wo, Wm1, Wm2,
                                             xb, Wcb, Wqkvb, Wob, Wm1b, Wm2b);

    // K2) QKV GEMM | bucket fill (atomic stall hidden under MFMA)
    fill_qkv_kernel<<<768 + 512, 256, 0, stream>>>(ei, cursor, bucket,
                                                   xb, Wqkvb, bqkv, qkvb);

    // K3) attention | aggregate
    agg_attn_kernel<<<256 + 2048, 512, 0, stream>>>(qkvb, ob, bucket, cursor, xb, shb);

    // K4) Wc | Wo GEMMs (+stats1/2)
    {
        dim3 g(NT / 128, 2);
        gemm_wcwo<<<g, 256, 0, stream>>>(shb, ob, Wcb, Wob, bc, bo, xb,
                                         hlocb, t2b, sum1, sq1, sum2, sq2);
    }

    // K5) MLP1 with comb fused into staging (writes comb to shb from y==0)
    {
        dim3 g(NT / 128, 2);
        gemm_m1c<<<g, 256, 0, stream>>>(hlocb, t2b, sum1, sq1, gn1, bn1b,
                                        sum2, sq2, gn2, bn2b, shb, Wm1b, bm1, hidb);
    }

    // K6) MLP2 (+stats3)
    {
        dim3 g(NT / 128, 1);
        gemm_mfma<false, 2, true><<<g, 256, 0, stream>>>(
            hidb, Wm2b, bm2, shb, out2b, sum3, sq3, NT, 128, 256);
    }

    // K7) final BN
    final_bn<<<NT * CCH / 8 / 256, 256, 0, stream>>>(out2b, sum3, sq3, gn3, bn3b, outp);
}

// Round 14
// 251.208 us; speedup vs baseline: 1.0364x; 1.0058x over previous
//
#include <hip/hip_runtime.h>
#include <cstddef>

#define NT    32768
#define CCH   128
#define BB    64
#define NNODE 512
#define NHEAD 4
#define DHEAD 32
#define EE    524288
#define EPS   1e-5f
#define MAXDEG 96
#define VTS   524

typedef unsigned short u16;
typedef unsigned int   u32;
typedef __attribute__((ext_vector_type(8))) short short8;
typedef __attribute__((ext_vector_type(4))) short short4v;
typedef __attribute__((ext_vector_type(4))) float f32x4;

__device__ __forceinline__ float b2f(u32 w) { return __uint_as_float(w << 16); }
__device__ __forceinline__ u16 f2b(float f) {
    u32 u = __float_as_uint(f);
    u += 0x7FFF + ((u >> 16) & 1);   // RNE
    return (u16)(u >> 16);
}

__device__ __forceinline__ void fill4(const int* __restrict__ ei, int* __restrict__ cursor,
                                      u16* __restrict__ bucket, int e) {
    int4 sv = *(const int4*)(ei + e);
    int4 dv = *(const int4*)(ei + EE + e);
    int p0 = atomicAdd(cursor + dv.x, 1);
    int p1 = atomicAdd(cursor + dv.y, 1);
    int p2 = atomicAdd(cursor + dv.z, 1);
    int p3 = atomicAdd(cursor + dv.w, 1);
    if (p0 < MAXDEG) bucket[dv.x * MAXDEG + p0] = (u16)sv.x;
    if (p1 < MAXDEG) bucket[dv.y * MAXDEG + p1] = (u16)sv.y;
    if (p2 < MAXDEG) bucket[dv.z * MAXDEG + p2] = (u16)sv.z;
    if (p3 < MAXDEG) bucket[dv.w * MAXDEG + p3] = (u16)sv.w;
}

// ---------------- K1: convert (blocks 0..2119) | fill half 1 (blocks 2120..2375) ----------------
__global__ __launch_bounds__(256) void convert_fill_kernel(const float* __restrict__ x,
                                                           const float* __restrict__ Wc,
                                                           const float* __restrict__ Wqkv,
                                                           const float* __restrict__ Wo,
                                                           const float* __restrict__ Wm1,
                                                           const float* __restrict__ Wm2,
                                                           u16* __restrict__ xb,
                                                           u16* __restrict__ Wcb,
                                                           u16* __restrict__ Wqkvb,
                                                           u16* __restrict__ Wob,
                                                           u16* __restrict__ Wm1b,
                                                           u16* __restrict__ Wm2b,
                                                           const int* __restrict__ ei,
                                                           int* __restrict__ cursor,
                                                           u16* __restrict__ bucket) {
    if (blockIdx.x >= 2120) {
        int t = (blockIdx.x - 2120) * 256 + threadIdx.x;
        fill4(ei, cursor, bucket, t * 4);   // edges [0, 262144)
        return;
    }
    int r = blockIdx.x * 256 + threadIdx.x;
    const float* src; u16* dst;
    if (r < 524288) { src = x; dst = xb; }
    else if ((r -= 524288) < 2048) { src = Wc; dst = Wcb; }
    else if ((r -= 2048) < 6144) { src = Wqkv; dst = Wqkvb; }
    else if ((r -= 6144) < 2048) { src = Wo; dst = Wob; }
    else if ((r -= 2048) < 4096) { src = Wm1; dst = Wm1b; }
    else { r -= 4096; src = Wm2; dst = Wm2b; }
    size_t base = (size_t)r * 8;
    float4 a = *(const float4*)(src + base);
    float4 b = *(const float4*)(src + base + 4);
    uint4 u;
    u.x = (u32)f2b(a.x) | ((u32)f2b(a.y) << 16);
    u.y = (u32)f2b(a.z) | ((u32)f2b(a.w) << 16);
    u.z = (u32)f2b(b.x) | ((u32)f2b(b.y) << 16);
    u.w = (u32)f2b(b.z) | ((u32)f2b(b.w) << 16);
    *(uint4*)(dst + base) = u;
}

// ---------------- K2: QKV GEMM (blocks 0..767) | fill half 2 (blocks 768..1023) ----------------
__global__ __launch_bounds__(256) void fill_qkv_kernel(const int* __restrict__ ei,
                                                       int* __restrict__ cursor,
                                                       u16* __restrict__ bucket,
                                                       const u16* __restrict__ xb,
                                                       const u16* __restrict__ Wqkvb,
                                                       const float* __restrict__ bqkv,
                                                       u16* __restrict__ qkvb) {
    __shared__ __align__(16) char smem[25600];
    int tid = threadIdx.x;
    if (blockIdx.x >= 768) {
        int t = (blockIdx.x - 768) * 256 + tid;
        fill4(ei, cursor, bucket, 262144 + t * 4);   // edges [262144, 524288)
        return;
    }
    int bx = blockIdx.x;
    int y = bx >> 8;
    int m0 = (bx & 255) * 128;
    const u16* W = Wqkvb + (size_t)y * 128 * 128;
    const float* bias = bqkv + y * 128;
    u16* As = (u16*)smem;                 // 8192 B
    u16* Bs = (u16*)(smem + 8192);        // 8192 B
    u16* Cs = (u16*)(smem + 16384);       // 9216 B

    int lane = tid & 63, wave = tid >> 6;
    int wm = (wave & 1) * 64, wn = (wave >> 1) * 64;
    int l15 = lane & 15, l4 = lane >> 4;

    f32x4 zero = {0.f, 0.f, 0.f, 0.f};
    f32x4 acc[4][4];
#pragma unroll
    for (int i = 0; i < 4; ++i)
#pragma unroll
        for (int j = 0; j < 4; ++j) acc[i][j] = zero;

    int srow = tid >> 2;
    int scol = (tid & 3) * 8;

    uint4 a0 = *(const uint4*)(xb + (size_t)(m0 + srow) * 128 + scol);
    uint4 a1 = *(const uint4*)(xb + (size_t)(m0 + srow + 64) * 128 + scol);
    uint4 b0 = *(const uint4*)(W + (size_t)srow * 128 + scol);
    uint4 b1 = *(const uint4*)(W + (size_t)(srow + 64) * 128 + scol);
    for (int ki = 0; ki < 4; ++ki) {
        if (ki) __syncthreads();
        *(uint4*)&As[srow * 32 + scol] = a0;
        *(uint4*)&As[(srow + 64) * 32 + scol] = a1;
        *(uint4*)&Bs[srow * 32 + scol] = b0;
        *(uint4*)&Bs[(srow + 64) * 32 + scol] = b1;
        if (ki < 3) {
            int k0 = (ki + 1) * 32;
            a0 = *(const uint4*)(xb + (size_t)(m0 + srow) * 128 + k0 + scol);
            a1 = *(const uint4*)(xb + (size_t)(m0 + srow + 64) * 128 + k0 + scol);
            b0 = *(const uint4*)(W + (size_t)srow * 128 + k0 + scol);
            b1 = *(const uint4*)(W + (size_t)(srow + 64) * 128 + k0 + scol);
        }
        __syncthreads();
        short8 af[4], bf[4];
#pragma unroll
        for (int t = 0; t < 4; ++t) {
            af[t] = *(const short8*)&As[(wm + t * 16 + l15) * 32 + l4 * 8];
            bf[t] = *(const short8*)&Bs[(wn + t * 16 + l15) * 32 + l4 * 8];
        }
#pragma unroll
        for (int mt = 0; mt < 4; ++mt)
#pragma unroll
            for (int nt = 0; nt < 4; ++nt)
                acc[mt][nt] = __builtin_amdgcn_mfma_f32_16x16x32_bf16(af[mt], bf[nt], acc[mt][nt], 0, 0, 0);
    }

    int rl = lane >> 3;
    int cg = lane & 7;
    u16* Cw = Cs + wave * 16 * 72;
#pragma unroll
    for (int mt = 0; mt < 4; ++mt) {
#pragma unroll
        for (int nt = 0; nt < 4; ++nt) {
            float bs = bias[wn + nt * 16 + l15];
#pragma unroll
            for (int r = 0; r < 4; ++r)
                Cw[(l4 * 4 + r) * 72 + nt * 16 + l15] = f2b(acc[mt][nt][r] + bs);
        }
#pragma unroll
        for (int p = 0; p < 2; ++p) {
            int lrow = p * 8 + rl;
            uint4 wv = *(const uint4*)&Cw[lrow * 72 + cg * 8];
            int grow = m0 + wm + mt * 16 + lrow;
            *(uint4*)(qkvb + (size_t)grow * 384 + y * 128 + wn + cg * 8) = wv;
        }
    }
}

// ---------------- K3: attention (blocks 0..255) | aggregate (blocks 256..2303), 512 threads ----------------
__global__ __launch_bounds__(512) void agg_attn_kernel(const u16* __restrict__ qkvb,
                                                       u16* __restrict__ ob,
                                                       const u16* __restrict__ bucket,
                                                       const int* __restrict__ cursor,
                                                       const u16* __restrict__ xb,
                                                       u16* __restrict__ aggb) {
    __shared__ __align__(16) char smem[74496];
    int tid = threadIdx.x;
    if (blockIdx.x >= 256) {
        int* srcs = (int*)smem;              // [16][96]
        int ln = tid >> 5;
        int c4 = tid & 31;
        int n = (blockIdx.x - 256) * 16 + ln;
        int d = min(cursor[n], MAXDEG);
        for (int j = c4; j < d; j += 32) srcs[ln * MAXDEG + j] = bucket[n * MAXDEG + j];
        __syncthreads();
        float s0 = 0.f, s1 = 0.f, s2 = 0.f, s3 = 0.f;
        for (int j = 0; j < d; ++j) {
            uint2 w = *(const uint2*)(xb + (size_t)srcs[ln * MAXDEG + j] * CCH + c4 * 4);
            s0 += b2f(w.x & 0xffffu);
            s1 += b2f(w.x >> 16);
            s2 += b2f(w.y & 0xffffu);
            s3 += b2f(w.y >> 16);
        }
        float inv = 1.0f / fmaxf((float)d, 1.0f);
        uint2 out;
        out.x = (u32)f2b(s0 * inv) | ((u32)f2b(s1 * inv) << 16);
        out.y = (u32)f2b(s2 * inv) | ((u32)f2b(s3 * inv) << 16);
        *(uint2*)(aggb + (size_t)n * CCH + c4 * 4) = out;
        return;
    }
    u16* Ks = (u16*)smem;                    // 40960 B
    u16* Vt = (u16*)(smem + 40960);          // 33536 B
    int bh = blockIdx.x;
    int b = bh >> 2, h = bh & 3;
    int lane = tid & 63, wave = tid >> 6;
    int quad = lane >> 4, l15 = lane & 15;
    const float scale = 0.1767766952966369f;  // 1/sqrt(32)

    const u16* kvbase = qkvb + (size_t)b * 512 * 384 + 128 + h * 32;
    for (int idx = tid; idx < 2048; idx += 512) {
        int row = idx >> 2, c = idx & 3;
        *(uint4*)&Ks[row * 40 + c * 8] = *(const uint4*)(kvbase + (size_t)row * 384 + c * 8);
    }
    for (int idx = tid; idx < 2048; idx += 512) {
        int row = idx >> 2, c = idx & 3;
        uint4 u = *(const uint4*)(kvbase + 128 + (size_t)row * 384 + c * 8);
        u16 e[8];
        *(uint4*)e = u;
#pragma unroll
        for (int i = 0; i < 8; ++i) Vt[(c * 8 + i) * VTS + row] = e[i];
    }
    __syncthreads();

    f32x4 zero = {0.f, 0.f, 0.f, 0.f};
    for (int qt = 0; qt < 4; ++qt) {
        int qbase = wave * 64 + qt * 16;
        short8 qf = *(const short8*)(qkvb + (size_t)(b * 512 + qbase + l15) * 384 + h * 32 + quad * 8);
        float lq = 0.f;
        f32x4 oa[2] = {zero, zero};

        for (int kv0 = 0; kv0 < 512; kv0 += 64) {
            f32x4 s[4];
#pragma unroll
            for (int t = 0; t < 4; ++t) {
                short8 kb = *(const short8*)&Ks[(kv0 + t * 16 + l15) * 40 + quad * 8];
                s[t] = __builtin_amdgcn_mfma_f32_16x16x32_bf16(kb, qf, zero, 0, 0, 0);
            }
            short8 pa[4];
#pragma unroll
            for (int t = 0; t < 4; ++t) {
                float p0 = __expf(s[t][0] * scale);
                float p1 = __expf(s[t][1] * scale);
                float p2 = __expf(s[t][2] * scale);
                float p3 = __expf(s[t][3] * scale);
                lq += (p0 + p1) + (p2 + p3);
                short8 a8 = {(short)f2b(p0), (short)f2b(p1), (short)f2b(p2), (short)f2b(p3), 0, 0, 0, 0};
                pa[t] = a8;
            }
#pragma unroll
            for (int t = 0; t < 4; ++t) {
                int tbase = kv0 + t * 16;
#pragma unroll
                for (int n = 0; n < 2; ++n) {
                    short4v v4 = *(const short4v*)&Vt[(n * 16 + l15) * VTS + tbase + quad * 4];
                    short8 vb = {v4.x, v4.y, v4.z, v4.w, 0, 0, 0, 0};
                    oa[n] = __builtin_amdgcn_mfma_f32_16x16x32_bf16(pa[t], vb, oa[n], 0, 0, 0);
                }
            }
        }
        lq += __shfl_xor(lq, 16);
        lq += __shfl_xor(lq, 32);
        u16* op = ob + (size_t)(b * 512 + qbase) * 128 + h * 32;
#pragma unroll
        for (int r = 0; r < 4; ++r) {
            float Lr = __shfl(lq, quad * 4 + r);
            float inv = 1.0f / Lr;
#pragma unroll
            for (int n = 0; n < 2; ++n)
                op[(quad * 4 + r) * 128 + n * 16 + l15] = f2b(oa[n][r] * inv);
        }
    }
}

// ---------------- K4: Wc GEMM (y=0) | Wo GEMM (y=1) — both K=128, resid=xb, stats ----------------
__global__ __launch_bounds__(256) void gemm_wcwo(const u16* __restrict__ aggb,
                                                 const u16* __restrict__ ob,
                                                 const u16* __restrict__ Wcb,
                                                 const u16* __restrict__ Wob,
                                                 const float* __restrict__ bc,
                                                 const float* __restrict__ bo,
                                                 const u16* __restrict__ xb,
                                                 u16* __restrict__ hlocb,
                                                 u16* __restrict__ t2b,
                                                 float* __restrict__ sum1,
                                                 float* __restrict__ sq1,
                                                 float* __restrict__ sum2,
                                                 float* __restrict__ sq2) {
    __shared__ u16 As[128 * 32];
    __shared__ u16 Bs[128 * 32];
    __shared__ u16 Cs[4][16 * 72];
    __shared__ float csum[128];
    __shared__ float csq[128];
    int y = blockIdx.y;
    const u16* A = y ? ob : aggb;
    const u16* W = y ? Wob : Wcb;
    const float* bias = y ? bo : bc;
    u16* outb = y ? t2b : hlocb;
    float* sum = y ? sum2 : sum1;
    float* sumsq = y ? sq2 : sq1;

    int m0 = blockIdx.x * 128;
    int tid = threadIdx.x;
    int lane = tid & 63, wave = tid >> 6;
    int wm = (wave & 1) * 64, wn = (wave >> 1) * 64;
    int l15 = lane & 15, l4 = lane >> 4;

    if (tid < 128) { csum[tid] = 0.f; csq[tid] = 0.f; }

    f32x4 zero = {0.f, 0.f, 0.f, 0.f};
    f32x4 acc[4][4];
#pragma unroll
    for (int i = 0; i < 4; ++i)
#pragma unroll
        for (int j = 0; j < 4; ++j) acc[i][j] = zero;

    int srow = tid >> 2;
    int scol = (tid & 3) * 8;

    uint4 a0 = *(const uint4*)(A + (size_t)(m0 + srow) * 128 + scol);
    uint4 a1 = *(const uint4*)(A + (size_t)(m0 + srow + 64) * 128 + scol);
    uint4 b0 = *(const uint4*)(W + (size_t)srow * 128 + scol);
    uint4 b1 = *(const uint4*)(W + (size_t)(srow + 64) * 128 + scol);
    for (int ki = 0; ki < 4; ++ki) {
        if (ki) __syncthreads();
        *(uint4*)&As[srow * 32 + scol] = a0;
        *(uint4*)&As[(srow + 64) * 32 + scol] = a1;
        *(uint4*)&Bs[srow * 32 + scol] = b0;
        *(uint4*)&Bs[(srow + 64) * 32 + scol] = b1;
        if (ki < 3) {
            int k0 = (ki + 1) * 32;
            a0 = *(const uint4*)(A + (size_t)(m0 + srow) * 128 + k0 + scol);
            a1 = *(const uint4*)(A + (size_t)(m0 + srow + 64) * 128 + k0 + scol);
            b0 = *(const uint4*)(W + (size_t)srow * 128 + k0 + scol);
            b1 = *(const uint4*)(W + (size_t)(srow + 64) * 128 + k0 + scol);
        }
        __syncthreads();
        short8 af[4], bf[4];
#pragma unroll
        for (int t = 0; t < 4; ++t) {
            af[t] = *(const short8*)&As[(wm + t * 16 + l15) * 32 + l4 * 8];
            bf[t] = *(const short8*)&Bs[(wn + t * 16 + l15) * 32 + l4 * 8];
        }
#pragma unroll
        for (int mt = 0; mt < 4; ++mt)
#pragma unroll
            for (int nt = 0; nt < 4; ++nt)
                acc[mt][nt] = __builtin_amdgcn_mfma_f32_16x16x32_bf16(af[mt], bf[nt], acc[mt][nt], 0, 0, 0);
    }

    float ps[4] = {0.f, 0.f, 0.f, 0.f};
    float pq[4] = {0.f, 0.f, 0.f, 0.f};
    int rl = lane >> 3;
    int cg = lane & 7;
#pragma unroll
    for (int mt = 0; mt < 4; ++mt) {
#pragma unroll
        for (int nt = 0; nt < 4; ++nt) {
            int lcol = wn + nt * 16 + l15;
            float bs = bias[lcol];
#pragma unroll
            for (int r = 0; r < 4; ++r) {
                int row = m0 + wm + mt * 16 + l4 * 4 + r;
                float v = acc[mt][nt][r] + bs + b2f(xb[(size_t)row * 128 + lcol]);
                Cs[wave][(l4 * 4 + r) * 72 + nt * 16 + l15] = f2b(v);
                ps[nt] += v; pq[nt] += v * v;
            }
        }
#pragma unroll
        for (int p = 0; p < 2; ++p) {
            int lrow = p * 8 + rl;
            uint4 wv = *(const uint4*)&Cs[wave][lrow * 72 + cg * 8];
            int grow = m0 + wm + mt * 16 + lrow;
            *(uint4*)(outb + (size_t)grow * 128 + wn + cg * 8) = wv;
        }
    }
#pragma unroll
    for (int nt = 0; nt < 4; ++nt) {
        atomicAdd(&csum[wn + nt * 16 + l15], ps[nt]);
        atomicAdd(&csq[wn + nt * 16 + l15], pq[nt]);
    }
    __syncthreads();
    if (tid < 128) {
        atomicAdd(sum + tid, csum[tid]);
        atomicAdd(sumsq + tid, csq[tid]);
    }
}

// ---------------- bf16 MFMA GEMM (MLP2): dbuf + wide-store epilogue ----------------
template <bool RELU, int RESID, bool STATS>
__global__ __launch_bounds__(256) void gemm_mfma(const u16* __restrict__ A,
                                                 const u16* __restrict__ W,
                                                 const float* __restrict__ bias,
                                                 const u16* __restrict__ residb,
                                                 u16* __restrict__ outb,
                                                 float* __restrict__ sum,
                                                 float* __restrict__ sumsq,
                                                 int M, int N, int K) {
    __shared__ u16 As[128 * 32];
    __shared__ u16 Bs[128 * 32];
    __shared__ u16 Cs[4][16 * 72];
    __shared__ float csum[128];
    __shared__ float csq[128];
    int m0 = blockIdx.x * 128, n0 = blockIdx.y * 128;
    int tid = threadIdx.x;
    int lane = tid & 63, wave = tid >> 6;
    int wm = (wave & 1) * 64, wn = (wave >> 1) * 64;
    int l15 = lane & 15, l4 = lane >> 4;

    if (STATS) {
        if (tid < 128) { csum[tid] = 0.f; csq[tid] = 0.f; }
    }

    f32x4 zero = {0.f, 0.f, 0.f, 0.f};
    f32x4 acc[4][4];
#pragma unroll
    for (int i = 0; i < 4; ++i)
#pragma unroll
        for (int j = 0; j < 4; ++j) acc[i][j] = zero;

    int srow = tid >> 2;
    int scol = (tid & 3) * 8;

    int kIter = K >> 5;
    uint4 a0 = *(const uint4*)(A + (size_t)(m0 + srow) * K + scol);
    uint4 a1 = *(const uint4*)(A + (size_t)(m0 + srow + 64) * K + scol);
    uint4 b0 = *(const uint4*)(W + (size_t)(n0 + srow) * K + scol);
    uint4 b1 = *(const uint4*)(W + (size_t)(n0 + srow + 64) * K + scol);
    for (int ki = 0; ki < kIter; ++ki) {
        if (ki) __syncthreads();
        *(uint4*)&As[srow * 32 + scol] = a0;
        *(uint4*)&As[(srow + 64) * 32 + scol] = a1;
        *(uint4*)&Bs[srow * 32 + scol] = b0;
        *(uint4*)&Bs[(srow + 64) * 32 + scol] = b1;
        if (ki + 1 < kIter) {
            int k0 = (ki + 1) * 32;
            a0 = *(const uint4*)(A + (size_t)(m0 + srow) * K + k0 + scol);
            a1 = *(const uint4*)(A + (size_t)(m0 + srow + 64) * K + k0 + scol);
            b0 = *(const uint4*)(W + (size_t)(n0 + srow) * K + k0 + scol);
            b1 = *(const uint4*)(W + (size_t)(n0 + srow + 64) * K + k0 + scol);
        }
        __syncthreads();
        short8 af[4], bf[4];
#pragma unroll
        for (int t = 0; t < 4; ++t) {
            af[t] = *(const short8*)&As[(wm + t * 16 + l15) * 32 + l4 * 8];
            bf[t] = *(const short8*)&Bs[(wn + t * 16 + l15) * 32 + l4 * 8];
        }
#pragma unroll
        for (int mt = 0; mt < 4; ++mt)
#pragma unroll
            for (int nt = 0; nt < 4; ++nt)
                acc[mt][nt] = __builtin_amdgcn_mfma_f32_16x16x32_bf16(af[mt], bf[nt], acc[mt][nt], 0, 0, 0);
    }

    float ps[4] = {0.f, 0.f, 0.f, 0.f};
    float pq[4] = {0.f, 0.f, 0.f, 0.f};
    int rl = lane >> 3;
    int cg = lane & 7;
#pragma unroll
    for (int mt = 0; mt < 4; ++mt) {
#pragma unroll
        for (int nt = 0; nt < 4; ++nt) {
            int col = n0 + wn + nt * 16 + l15;
            float bs = bias[col];
#pragma unroll
            for (int r = 0; r < 4; ++r) {
                int row = m0 + wm + mt * 16 + l4 * 4 + r;
                float v = acc[mt][nt][r] + bs;
                if (RESID == 2) v += b2f(residb[(size_t)row * N + col]);
                if (RELU) v = fmaxf(v, 0.0f);
                Cs[wave][(l4 * 4 + r) * 72 + nt * 16 + l15] = f2b(v);
                if (STATS) { ps[nt] += v; pq[nt] += v * v; }
            }
        }
#pragma unroll
        for (int p = 0; p < 2; ++p) {
            int lrow = p * 8 + rl;
            uint4 wv = *(const uint4*)&Cs[wave][lrow * 72 + cg * 8];
            int grow = m0 + wm + mt * 16 + lrow;
            *(uint4*)(outb + (size_t)grow * N + n0 + wn + cg * 8) = wv;
        }
    }
    if (STATS) {
#pragma unroll
        for (int nt = 0; nt < 4; ++nt) {
            atomicAdd(&csum[wn + nt * 16 + l15], ps[nt]);
            atomicAdd(&csq[wn + nt * 16 + l15], pq[nt]);
        }
        __syncthreads();
        if (tid < 128) {
            atomicAdd(sum + n0 + tid, csum[tid]);
            atomicAdd(sumsq + n0 + tid, csq[tid]);
        }
    }
}

// ---------------- MLP1 GEMM with comb fused into A-staging; dbuf + wide stores ----------------
__global__ __launch_bounds__(256) void gemm_m1c(const u16* __restrict__ hlocb,
                                                const u16* __restrict__ t2b,
                                                const float* __restrict__ sum1,
                                                const float* __restrict__ sq1,
                                                const float* __restrict__ g1,
                                                const float* __restrict__ bt1,
                                                const float* __restrict__ sum2,
                                                const float* __restrict__ sq2,
                                                const float* __restrict__ g2,
                                                const float* __restrict__ bt2,
                                                u16* __restrict__ shb,
                                                const u16* __restrict__ Wm1b,
                                                const float* __restrict__ bm1,
                                                u16* __restrict__ hidb) {
    __shared__ u16 As[128 * 32];
    __shared__ u16 Bs[128 * 32];
    __shared__ u16 Cs[4][16 * 72];
    __shared__ float AF1[128], BF1[128], AF2[128], BF2[128];
    int tid = threadIdx.x;
    {
        int c = tid & 127;
        const float* sm = (tid < 128) ? sum1 : sum2;
        const float* sq = (tid < 128) ? sq1 : sq2;
        const float* g  = (tid < 128) ? g1 : g2;
        const float* bt = (tid < 128) ? bt1 : bt2;
        float m = sm[c] * (1.0f / NT);
        float v = sq[c] * (1.0f / NT) - m * m;
        float a = g[c] * rsqrtf(v + EPS);
        if (tid < 128) { AF1[c] = a; BF1[c] = bt[c] - m * a; }
        else           { AF2[c] = a; BF2[c] = bt[c] - m * a; }
    }
    int m0 = blockIdx.x * 128, n0 = blockIdx.y * 128;
    int lane = tid & 63, wave = tid >> 6;
    int wm = (wave & 1) * 64, wn = (wave >> 1) * 64;
    int l15 = lane & 15, l4 = lane >> 4;

    f32x4 zero = {0.f, 0.f, 0.f, 0.f};
    f32x4 acc[4][4];
#pragma unroll
    for (int i = 0; i < 4; ++i)
#pragma unroll
        for (int j = 0; j < 4; ++j) acc[i][j] = zero;

    int srow = tid >> 2;
    int scol = (tid & 3) * 8;
    bool wr = (blockIdx.y == 0);

    uint4 h0 = *(const uint4*)(hlocb + (size_t)(m0 + srow) * 128 + scol);
    uint4 h1 = *(const uint4*)(hlocb + (size_t)(m0 + srow + 64) * 128 + scol);
    uint4 t0 = *(const uint4*)(t2b + (size_t)(m0 + srow) * 128 + scol);
    uint4 t1 = *(const uint4*)(t2b + (size_t)(m0 + srow + 64) * 128 + scol);
    uint4 b0 = *(const uint4*)(Wm1b + (size_t)(n0 + srow) * 128 + scol);
    uint4 b1 = *(const uint4*)(Wm1b + (size_t)(n0 + srow + 64) * 128 + scol);
    __syncthreads();
    for (int ki = 0; ki < 4; ++ki) {
        int k0 = ki * 32;
        if (ki) __syncthreads();
        uint4 c0, c1;
        {
            const u32 hw[4] = {h0.x, h0.y, h0.z, h0.w};
            const u32 tw[4] = {t0.x, t0.y, t0.z, t0.w};
            u32 ow[4];
#pragma unroll
            for (int p = 0; p < 4; ++p) {
                int cc = k0 + scol + p * 2;
                float v0 = AF1[cc] * b2f(hw[p] & 0xffffu) + BF1[cc] + AF2[cc] * b2f(tw[p] & 0xffffu) + BF2[cc];
                float v1 = AF1[cc + 1] * b2f(hw[p] >> 16) + BF1[cc + 1] + AF2[cc + 1] * b2f(tw[p] >> 16) + BF2[cc + 1];
                ow[p] = (u32)f2b(v0) | ((u32)f2b(v1) << 16);
            }
            c0.x = ow[0]; c0.y = ow[1]; c0.z = ow[2]; c0.w = ow[3];
        }
        {
            const u32 hw[4] = {h1.x, h1.y, h1.z, h1.w};
            const u32 tw[4] = {t1.x, t1.y, t1.z, t1.w};
            u32 ow[4];
#pragma unroll
            for (int p = 0; p < 4; ++p) {
                int cc = k0 + scol + p * 2;
                float v0 = AF1[cc] * b2f(hw[p] & 0xffffu) + BF1[cc] + AF2[cc] * b2f(tw[p] & 0xffffu) + BF2[cc];
                float v1 = AF1[cc + 1] * b2f(hw[p] >> 16) + BF1[cc + 1] + AF2[cc + 1] * b2f(tw[p] >> 16) + BF2[cc + 1];
                ow[p] = (u32)f2b(v0) | ((u32)f2b(v1) << 16);
            }
            c1.x = ow[0]; c1.y = ow[1]; c1.z = ow[2]; c1.w = ow[3];
        }
        *(uint4*)&As[srow * 32 + scol] = c0;
        *(uint4*)&As[(srow + 64) * 32 + scol] = c1;
        *(uint4*)&Bs[srow * 32 + scol] = b0;
        *(uint4*)&Bs[(srow + 64) * 32 + scol] = b1;
        if (wr) {
            *(uint4*)(shb + (size_t)(m0 + srow) * 128 + k0 + scol) = c0;
            *(uint4*)(shb + (size_t)(m0 + srow + 64) * 128 + k0 + scol) = c1;
        }
        if (ki < 3) {
            int kn = k0 + 32;
            h0 = *(const uint4*)(hlocb + (size_t)(m0 + srow) * 128 + kn + scol);
            h1 = *(const uint4*)(hlocb + (size_t)(m0 + srow + 64) * 128 + kn + scol);
            t0 = *(const uint4*)(t2b + (size_t)(m0 + srow) * 128 + kn + scol);
            t1 = *(const uint4*)(t2b + (size_t)(m0 + srow + 64) * 128 + kn + scol);
            b0 = *(const uint4*)(Wm1b + (size_t)(n0 + srow) * 128 + kn + scol);
            b1 = *(const uint4*)(Wm1b + (size_t)(n0 + srow + 64) * 128 + kn + scol);
        }
        __syncthreads();
        short8 af[4], bf[4];
#pragma unroll
        for (int t = 0; t < 4; ++t) {
            af[t] = *(const short8*)&As[(wm + t * 16 + l15) * 32 + l4 * 8];
            bf[t] = *(const short8*)&Bs[(wn + t * 16 + l15) * 32 + l4 * 8];
        }
#pragma unroll
        for (int mt = 0; mt < 4; ++mt)
#pragma unroll
            for (int nt = 0; nt < 4; ++nt)
                acc[mt][nt] = __builtin_amdgcn_mfma_f32_16x16x32_bf16(af[mt], bf[nt], acc[mt][nt], 0, 0, 0);
    }

    int rl = lane >> 3;
    int cg = lane & 7;
#pragma unroll
    for (int mt = 0; mt < 4; ++mt) {
#pragma unroll
        for (int nt = 0; nt < 4; ++nt) {
            int col = n0 + wn + nt * 16 + l15;
            float bs = bm1[col];
#pragma unroll
            for (int r = 0; r < 4; ++r) {
                float v = fmaxf(acc[mt][nt][r] + bs, 0.0f);
                Cs[wave][(l4 * 4 + r) * 72 + nt * 16 + l15] = f2b(v);
            }
        }
#pragma unroll
        for (int p = 0; p < 2; ++p) {
            int lrow = p * 8 + rl;
            uint4 wv = *(const uint4*)&Cs[wave][lrow * 72 + cg * 8];
            int grow = m0 + wm + mt * 16 + lrow;
            *(uint4*)(hidb + (size_t)grow * 256 + n0 + wn + cg * 8) = wv;
        }
    }
}

// ---------------- final = bn3(out2), affine in-block, bf16 -> fp32 ----------------
__global__ __launch_bounds__(256) void final_bn(const u16* __restrict__ X,
                                                const float* __restrict__ sum3,
                                                const float* __restrict__ sq3,
                                                const float* __restrict__ g3,
                                                const float* __restrict__ bt3,
                                                float* __restrict__ outp) {
    __shared__ float A3[128], B3[128];
    int t = threadIdx.x;
    if (t < 128) {
        float m = sum3[t] * (1.0f / NT);
        float v = sq3[t] * (1.0f / NT) - m * m;
        float a = g3[t] * rsqrtf(v + EPS);
        A3[t] = a;
        B3[t] = bt3[t] - m * a;
    }
    __syncthreads();
    int i8 = blockIdx.x * 256 + t;
    size_t i = (size_t)i8 * 8;
    int c = (int)(i & (CCH - 1));
    uint4 u = *(const uint4*)(X + i);
    float x[8];
    x[0] = b2f(u.x & 0xffffu); x[1] = b2f(u.x >> 16);
    x[2] = b2f(u.y & 0xffffu); x[3] = b2f(u.y >> 16);
    x[4] = b2f(u.z & 0xffffu); x[5] = b2f(u.z >> 16);
    x[6] = b2f(u.w & 0xffffu); x[7] = b2f(u.w >> 16);
    float4 o0, o1;
    o0.x = A3[c + 0] * x[0] + B3[c + 0];
    o0.y = A3[c + 1] * x[1] + B3[c + 1];
    o0.z = A3[c + 2] * x[2] + B3[c + 2];
    o0.w = A3[c + 3] * x[3] + B3[c + 3];
    o1.x = A3[c + 4] * x[4] + B3[c + 4];
    o1.y = A3[c + 5] * x[5] + B3[c + 5];
    o1.z = A3[c + 6] * x[6] + B3[c + 6];
    o1.w = A3[c + 7] * x[7] + B3[c + 7];
    *(float4*)(outp + i) = o0;
    *(float4*)(outp + i + 4) = o1;
}

extern "C" void kernel_launch(void* const* d_in, const int* in_sizes, int n_in,
                              void* d_out, int out_size, void* d_ws, size_t ws_size,
                              hipStream_t stream) {
    const float* x    = (const float*)d_in[0];
    const int*   ei   = (const int*)d_in[1];
    const float* Wc   = (const float*)d_in[2];
    const float* bc   = (const float*)d_in[3];
    const float* Wqkv = (const float*)d_in[4];
    const float* bqkv = (const float*)d_in[5];
    const float* Wo   = (const float*)d_in[6];
    const float* bo   = (const float*)d_in[7];
    const float* gn1  = (const float*)d_in[8];
    const float* bn1b = (const float*)d_in[9];
    const float* gn2  = (const float*)d_in[10];
    const float* bn2b = (const float*)d_in[11];
    const float* gn3  = (const float*)d_in[12];
    const float* bn3b = (const float*)d_in[13];
    const float* Wm1  = (const float*)d_in[14];
    const float* bm1  = (const float*)d_in[15];
    const float* Wm2  = (const float*)d_in[16];
    const float* bm2  = (const float*)d_in[17];
    float* outp = (float*)d_out;

    char* w = (char*)d_ws;
    const size_t MB = 1024 * 1024;
    u16* xb    = (u16*)(w);                     //  8 MB
    u16* hlocb = (u16*)(w + 8 * MB);            //  8 MB
    u16* t2b   = (u16*)(w + 16 * MB);           //  8 MB  h_attn
    u16* out2b = (u16*)(w + 24 * MB);           //  8 MB
    u16* qkvb  = (u16*)(w + 32 * MB);           // 24 MB
    u16* hidb  = (u16*)(w + 56 * MB);           // 16 MB  [NT,256]
    u16* shb   = (u16*)(w + 72 * MB);           //  8 MB  agg -> comb
    u16* bucket = (u16*)(w + 80 * MB);          //  6 MB
    int* cursor = (int*)(w + 92 * MB);          // 128 KB
    float* stats = (float*)(w + 92 * MB + 128 * 1024);
    u16* Wcb   = (u16*)(w + 93 * MB);
    u16* Wqkvb = Wcb + 16384;
    u16* Wob   = Wqkvb + 49152;
    u16* Wm1b  = Wob + 16384;
    u16* Wm2b  = Wm1b + 32768;
    u16* ob    = (u16*)(w + 94 * MB);           //  8 MB  attention output
    float* sum1 = stats;        float* sq1 = stats + 128;
    float* sum2 = stats + 256;  float* sq2 = stats + 384;
    float* sum3 = stats + 512;  float* sq3 = stats + 640;

    hipMemsetAsync(cursor, 0, 128 * 1024 + 6 * 128 * 4, stream);

    // K1) conversions | fill half 1
    convert_fill_kernel<<<2120 + 256, 256, 0, stream>>>(x, Wc, Wqkv, Wo, Wm1, Wm2,
                                                        xb, Wcb, Wqkvb, Wob, Wm1b, Wm2b,
                                                        ei, cursor, bucket);

    // K2) QKV GEMM | fill half 2
    fill_qkv_kernel<<<768 + 256, 256, 0, stream>>>(ei, cursor, bucket,
                                                   xb, Wqkvb, bqkv, qkvb);

    // K3) attention | aggregate
    agg_attn_kernel<<<256 + 2048, 512, 0, stream>>>(qkvb, ob, bucket, cursor, xb, shb);

    // K4) Wc | Wo GEMMs (+stats1/2)
    {
        dim3 g(NT / 128, 2);
        gemm_wcwo<<<g, 256, 0, stream>>>(shb, ob, Wcb, Wob, bc, bo, xb,
                                         hlocb, t2b, sum1, sq1, sum2, sq2);
    }

    // K5) MLP1 with comb fused into staging (writes comb to shb from y==0)
    {
        dim3 g(NT / 128, 2);
        gemm_m1c<<<g, 256, 0, stream>>>(hlocb, t2b, sum1, sq1, gn1, bn1b,
                                        sum2, sq2, gn2, bn2b, shb, Wm1b, bm1, hidb);
    }

    // K6) MLP2 (+stats3)
    {
        dim3 g(NT / 128, 1);
        gemm_mfma<false, 2, true><<<g, 256, 0, stream>>>(
            hidb, Wm2b, bm2, shb, out2b, sum3, sq3, NT, 128, 256);
    }

    // K7) final BN
    final_bn<<<NT * CCH / 8 / 256, 256, 0, stream>>>(out2b, sum3, sq3, gn3, bn3b, outp);
}